// Round 3
// baseline (1488.280 us; speedup 1.0000x reference)
//
#include <hip/hip_runtime.h>

#define GN_EPS 1e-5f

typedef _Float16 half8 __attribute__((ext_vector_type(8)));
typedef float floatx4 __attribute__((ext_vector_type(4)));

__device__ __forceinline__ float sigmoidf_(float x){ return 1.0f/(1.0f+__expf(-x)); }
__device__ __forceinline__ float bcast_(float v, int k){
  return __int_as_float(__builtin_amdgcn_readlane(__float_as_int(v), k));
}

// ================= CSR build =================
__global__ void cnt_init_kernel(int* cnt, int n){
  int i = blockIdx.x*blockDim.x+threadIdx.x;
  if (i < n) cnt[i] = 1;  // self loop
}
__global__ void cnt_kernel(const int* __restrict__ ei, int* cnt, int E){
  int e = blockIdx.x*blockDim.x+threadIdx.x;
  if (e < E) atomicAdd(&cnt[ei[E+e]], 1);
}
__global__ void dis_from_cnt_kernel(const int* __restrict__ cnt, float* dis, int n){
  int i = blockIdx.x*blockDim.x+threadIdx.x;
  if (i < n) dis[i] = rsqrtf((float)cnt[i]);
}
// 3-dispatch exclusive scan (n <= 256*256)
__global__ __launch_bounds__(256) void scan1_kernel(const int* __restrict__ cnt,
                                                    int* loc, int* bsum, int n){
  __shared__ int s[256];
  int t = threadIdx.x, i = blockIdx.x*256 + t;
  int v = (i < n) ? cnt[i] : 0;
  s[t] = v; __syncthreads();
  #pragma unroll
  for (int d = 1; d < 256; d <<= 1){
    int u = (t >= d) ? s[t-d] : 0; __syncthreads();
    s[t] += u; __syncthreads();
  }
  if (i < n) loc[i] = s[t] - v;
  if (t == 255) bsum[blockIdx.x] = s[255];
}
__global__ __launch_bounds__(256) void scan2_kernel(int* bsum, int nb){
  __shared__ int s[256];
  int t = threadIdx.x;
  int v = (t < nb) ? bsum[t] : 0;
  s[t] = v; __syncthreads();
  #pragma unroll
  for (int d = 1; d < 256; d <<= 1){
    int u = (t >= d) ? s[t-d] : 0; __syncthreads();
    s[t] += u; __syncthreads();
  }
  if (t < nb) bsum[t] = s[t] - v;
}
__global__ void scan3_kernel(const int* __restrict__ loc, const int* __restrict__ bsum,
                             int* rowptr, int n, int total){
  int i = blockIdx.x*blockDim.x+threadIdx.x;
  if (i < n) rowptr[i] = loc[i] + bsum[i >> 8];
  if (i == 0) rowptr[n] = total;
}
__global__ void scatter_kernel(const int* __restrict__ ei, const float* __restrict__ ea,
                               const int* __restrict__ rowptr, int* fill,
                               int* src, _Float16* ea2, int E, int n){
  int idx = blockIdx.x*blockDim.x+threadIdx.x;
  int tot = E + n;
  if (idx >= tot) return;
  int r, c; float v;
  if (idx < E){ r = ei[idx]; c = ei[E+idx]; v = ea[idx]; }
  else        { r = c = idx - E; v = 1.0f; }
  int j = rowptr[c] + atomicAdd(&fill[c], 1);
  src[j] = r; ea2[j] = (_Float16)v;
}

// ================= node matvec kernels =================
template<int K_IN, int C_OUT>
__global__ __launch_bounds__(256) void mm1_kernel(
    const float* __restrict__ x, const float* __restrict__ W,
    const float* __restrict__ b, float* __restrict__ y, int n){
  __shared__ float sW[K_IN*C_OUT];
  for (int i = threadIdx.x; i < K_IN*C_OUT; i += 256) sW[i] = W[i];
  __syncthreads();
  const int lane = threadIdx.x & 63;
  const int col  = (lane < C_OUT) ? lane : 0;
  const float bias = b[col];
  int wid = (blockIdx.x*256 + threadIdx.x) >> 6;
  int nw  = (gridDim.x*256) >> 6;
  for (int i = wid; i < n; i += nw){
    float xv = (lane < K_IN) ? x[i*K_IN + lane] : 0.0f;
    float a0 = bias, a1 = 0.0f;
    #pragma unroll
    for (int k = 0; k < K_IN; k += 2){
      a0 += bcast_(xv, k  ) * sW[(k  )*C_OUT + col];
      a1 += bcast_(xv, k+1) * sW[(k+1)*C_OUT + col];
    }
    if (lane < C_OUT) y[i*C_OUT + lane] = a0 + a1;
  }
}

// P = h@gw1[0:64]+b1 (f32), Qh = (f16)(h@gw1[64:128])
__global__ __launch_bounds__(256) void pq_kernel(
    const float* __restrict__ h, const float* __restrict__ w1,
    const float* __restrict__ b1, float* __restrict__ P, _Float16* __restrict__ Qh, int n){
  __shared__ float sW[128*64];
  for (int i = threadIdx.x; i < 128*64; i += 256) sW[i] = w1[i];
  __syncthreads();
  const int lane = threadIdx.x & 63;
  const float bias = b1[lane];
  int wid = (blockIdx.x*256 + threadIdx.x) >> 6;
  int nw  = (gridDim.x*256) >> 6;
  for (int i = wid; i < n; i += nw){
    float hv = h[i*64 + lane];
    float ap0 = bias, ap1 = 0.f, aq0 = 0.f, aq1 = 0.f;
    #pragma unroll
    for (int k = 0; k < 64; k += 2){
      float b0 = bcast_(hv, k), b1v = bcast_(hv, k+1);
      ap0 += b0  * sW[(k     )*64 + lane];
      aq0 += b0  * sW[(64+k  )*64 + lane];
      ap1 += b1v * sW[(k+1   )*64 + lane];
      aq1 += b1v * sW[(64+k+1)*64 + lane];
    }
    P[(size_t)i*64+lane]  = ap0 + ap1;
    Qh[(size_t)i*64+lane] = (_Float16)(aq0 + aq1);
  }
}

// dual-input matvec (K=128): acc = [in1, in2(*dis)] @ W + b
// MODE 0: out = sigmoid(acc)  (z);   MODE 3: out = acc (fc1, no dis)
template<int MODE>
__global__ __launch_bounds__(256) void mm2_kernel(
    const float* __restrict__ in1, const float* __restrict__ in2,
    const float* __restrict__ dis,
    const float* __restrict__ W, const float* __restrict__ b,
    float* __restrict__ out, int n){
  __shared__ float sW[128*64];
  for (int i = threadIdx.x; i < 128*64; i += 256) sW[i] = W[i];
  __syncthreads();
  const int lane = threadIdx.x & 63;
  const float bias = b[lane];
  int wid = (blockIdx.x*256 + threadIdx.x) >> 6;
  int nw  = (gridDim.x*256) >> 6;
  for (int i = wid; i < n; i += nw){
    float v1 = in1[(size_t)i*64 + lane];
    float v2 = in2[(size_t)i*64 + lane];
    if (MODE != 3) v2 *= dis[i];
    float a0 = bias, a1 = 0.f;
    #pragma unroll
    for (int k = 0; k < 64; ++k){
      a0 += bcast_(v1, k) * sW[(k   )*64 + lane];
      a1 += bcast_(v2, k) * sW[(64+k)*64 + lane];
    }
    float acc = a0 + a1;
    out[(size_t)i*64 + lane] = (MODE == 0) ? sigmoidf_(acc) : acc;
  }
}

// fused GRU: r = sigmoid([h, a]@rw+rb); hc = relu([r*h, a]@hw+hb);
// aggr <- (1-z)*h + z*hc   (in-place over aggr; z precomputed in zbuf)
__global__ __launch_bounds__(256) void gru_kernel(
    const float* __restrict__ h, float* __restrict__ aggr,
    const float* __restrict__ dis, const float* __restrict__ zbuf,
    const float* __restrict__ rw, const float* __restrict__ rb,
    const float* __restrict__ hw, const float* __restrict__ hb, int n){
  __shared__ float sR[128*64];
  __shared__ float sH[128*64];
  for (int i = threadIdx.x; i < 128*64; i += 256){ sR[i] = rw[i]; sH[i] = hw[i]; }
  __syncthreads();
  const int lane = threadIdx.x & 63;
  const float rbv = rb[lane], hbv = hb[lane];
  int wid = (blockIdx.x*256 + threadIdx.x) >> 6;
  int nw  = (gridDim.x*256) >> 6;
  for (int i = wid; i < n; i += nw){
    float hv = h[(size_t)i*64 + lane];
    float av = aggr[(size_t)i*64 + lane] * dis[i];
    float r0 = rbv, r1 = 0.f;
    #pragma unroll
    for (int k = 0; k < 64; ++k){
      r0 += bcast_(hv, k) * sR[(k   )*64 + lane];
      r1 += bcast_(av, k) * sR[(64+k)*64 + lane];
    }
    float rh = sigmoidf_(r0 + r1) * hv;
    float c0 = hbv, c1 = 0.f;
    #pragma unroll
    for (int k = 0; k < 64; ++k){
      c0 += bcast_(rh, k) * sH[(k   )*64 + lane];
      c1 += bcast_(av, k) * sH[(64+k)*64 + lane];
    }
    float hc = fmaxf(c0 + c1, 0.f);
    float zv = zbuf[(size_t)i*64 + lane];
    aggr[(size_t)i*64 + lane] = (1.f - zv)*hv + zv*hc;
  }
}

// ================= CSR edge kernel: wave per node, register accumulation =================
__global__ __launch_bounds__(256) void edge_csr_kernel(
    const int* __restrict__ rowptr, const int* __restrict__ src,
    const _Float16* __restrict__ ea2,
    const float* __restrict__ P, const _Float16* __restrict__ Qh,
    const float* __restrict__ h, const float* __restrict__ dis,
    const float* __restrict__ w2, const float* __restrict__ b2,
    const float* __restrict__ w1e, const float* __restrict__ w3,
    const float* __restrict__ b3,
    float* __restrict__ aggr, int n)
{
  const int lane = threadIdx.x & 63;
  const int g16  = lane >> 4;   // k-chunk group / D-row group
  const int l16  = lane & 15;   // edge-in-tile (A) / column-in-tile (B, D)

  // B fragments: col = l16 within c-tile t, k = kh*32 + g16*8 + j
  half8 bfrag[4][2];
  #pragma unroll
  for (int t = 0; t < 4; ++t)
    #pragma unroll
    for (int kh = 0; kh < 2; ++kh)
      #pragma unroll
      for (int j = 0; j < 8; ++j)
        bfrag[t][kh][j] = (_Float16)w2[(kh*32 + g16*8 + j)*64 + t*16 + l16];

  float w1f[16];
  #pragma unroll
  for (int kh = 0; kh < 2; ++kh)
    #pragma unroll
    for (int j = 0; j < 8; ++j)
      w1f[kh*8+j] = w1e[kh*32 + g16*8 + j];

  float w3f[4], b2f[4];
  #pragma unroll
  for (int t = 0; t < 4; ++t){ w3f[t] = w3[t*16 + l16]; b2f[t] = b2[t*16 + l16]; }
  const float b3v = b3[0];

  int wid = (blockIdx.x*blockDim.x + threadIdx.x) >> 6;
  int nw  = (gridDim.x*blockDim.x) >> 6;

  for (int c = wid; c < n; c += nw){
    const int base = rowptr[c], endp = rowptr[c+1];
    // P[c] chunk this lane needs: k = kh*32 + g16*8 + j
    float pcv[16];
    {
      const float* pr = P + (size_t)c*64 + g16*8;
      float4 a0 = *(const float4*)(pr);
      float4 a1 = *(const float4*)(pr+4);
      float4 a2 = *(const float4*)(pr+32);
      float4 a3 = *(const float4*)(pr+36);
      pcv[0]=a0.x; pcv[1]=a0.y; pcv[2]=a0.z; pcv[3]=a0.w;
      pcv[4]=a1.x; pcv[5]=a1.y; pcv[6]=a1.z; pcv[7]=a1.w;
      pcv[8]=a2.x; pcv[9]=a2.y; pcv[10]=a2.z; pcv[11]=a2.w;
      pcv[12]=a3.x; pcv[13]=a3.y; pcv[14]=a3.z; pcv[15]=a3.w;
    }
    float accv = 0.f;  // aggregated value for col = lane

    for (int t = base; t < endp; t += 16){
      int m = endp - t; if (m > 16) m = 16;
      int j  = t + ((l16 < m) ? l16 : (m-1));
      int r  = src[j];
      float eav = (float)ea2[j];
      float dv  = dis[r];   // pre-gathered, broadcast later via readlane

      // A fragments: row = l16 (edge), k = kh*32 + g16*8 + j8
      half8 afrag[2];
      #pragma unroll
      for (int kh = 0; kh < 2; ++kh){
        half8 hq = *(const half8*)(Qh + (size_t)r*64 + kh*32 + g16*8);
        #pragma unroll
        for (int j8 = 0; j8 < 8; ++j8){
          float g = pcv[kh*8+j8] + (float)hq[j8] + eav*w1f[kh*8+j8];
          afrag[kh][j8] = (_Float16)fmaxf(g, 0.0f);
        }
      }

      floatx4 acc[4];
      #pragma unroll
      for (int t4 = 0; t4 < 4; ++t4){
        acc[t4][0]=b2f[t4]; acc[t4][1]=b2f[t4]; acc[t4][2]=b2f[t4]; acc[t4][3]=b2f[t4];
      }
      #pragma unroll
      for (int t4 = 0; t4 < 4; ++t4){
        acc[t4] = __builtin_amdgcn_mfma_f32_16x16x32_f16(afrag[0], bfrag[t4][0], acc[t4], 0, 0, 0);
        acc[t4] = __builtin_amdgcn_mfma_f32_16x16x32_f16(afrag[1], bfrag[t4][1], acc[t4], 0, 0, 0);
      }

      // gate partials: edge g16*4+rg, this lane's column l16 (4 tiles)
      float s[4] = {0.f,0.f,0.f,0.f};
      #pragma unroll
      for (int t4 = 0; t4 < 4; ++t4)
        #pragma unroll
        for (int rg = 0; rg < 4; ++rg)
          s[rg] += fmaxf(acc[t4][rg], 0.0f) * w3f[t4];
      #pragma unroll
      for (int rg = 0; rg < 4; ++rg){
        #pragma unroll
        for (int off = 1; off < 16; off <<= 1)
          s[rg] += __shfl_xor(s[rg], off);
        s[rg] = sigmoidf_(s[rg] + b3v);
      }
      // gate of edge i: lanes (i>>2)*16.., slot i&3

      for (int i = 0; i < m; ++i){
        float gi = bcast_(s[i & 3], (i >> 2) * 16);
        float f  = gi * bcast_(dv, i);
        int ri   = __builtin_amdgcn_readlane(r, i);
        accv += f * h[(size_t)ri*64 + lane];
      }
    }
    aggr[(size_t)c*64 + lane] = accv;
  }
}

// ================= graph norm =================
template<int C>
__global__ __launch_bounds__(256) void norm_stats_kernel(
    const float* __restrict__ x, int n, float* __restrict__ stats){
  __shared__ float ssum[256], ssq[256];
  const int tid = threadIdx.x;
  const int c = tid % C;
  int row = (blockIdx.x*256 + tid) / C;
  int stride = (gridDim.x*256) / C;
  float s = 0.f, q = 0.f;
  for (int i = row; i < n; i += stride){
    float v = x[(size_t)i*C + c];
    s += v; q += v*v;
  }
  ssum[tid] = s; ssq[tid] = q;
  __syncthreads();
  if (tid < C){
    float S = 0.f, Q2 = 0.f;
    for (int t = tid; t < 256; t += C){ S += ssum[t]; Q2 += ssq[t]; }
    atomicAdd(&stats[tid], S);
    atomicAdd(&stats[C + tid], Q2);
  }
}

template<int C, int RELU, int DUAL>
__global__ __launch_bounds__(256) void norm_apply_kernel(
    const float* __restrict__ x, const float* __restrict__ stats,
    const float* __restrict__ w, const float* __restrict__ b,
    const float* __restrict__ ms, float* __restrict__ y,
    float* __restrict__ y2, int n){
  const float invN = 1.0f / (float)n;
  size_t idx = blockIdx.x*256 + threadIdx.x;
  size_t step = gridDim.x*256;
  size_t tot = (size_t)n*C;
  for (; idx < tot; idx += step){
    int c = idx % C;
    float mean = stats[c] * invN;
    float mm = mean * ms[c];
    float var = stats[C + c]*invN - mm*(2.0f*mean - mm);
    float inv = rsqrtf(fmaxf(var, 0.0f) + GN_EPS);
    float v = (x[idx] - mm)*inv*w[c] + b[c];
    if (RELU) v = fmaxf(v, 0.0f);
    y[idx] = v;
    if (DUAL) y2[idx] = v;
  }
}

// ================= fc2 =================
__global__ void fc2_kernel(
    const float* __restrict__ x, const float* __restrict__ w,
    const float* __restrict__ b, float* __restrict__ out, int n){
  int i = blockIdx.x*blockDim.x + threadIdx.x;
  if (i >= n) return;
  float a0 = b[0], a1 = b[1];
  const float4* xr = (const float4*)(x + (size_t)i*64);
  #pragma unroll
  for (int k4 = 0; k4 < 16; ++k4){
    float4 v = xr[k4];
    int k = k4*4;
    a0 += v.x*w[(k+0)*2+0] + v.y*w[(k+1)*2+0] + v.z*w[(k+2)*2+0] + v.w*w[(k+3)*2+0];
    a1 += v.x*w[(k+0)*2+1] + v.y*w[(k+1)*2+1] + v.z*w[(k+2)*2+1] + v.w*w[(k+3)*2+1];
  }
  out[i*2+0] = a0;
  out[i*2+1] = a1;
}

extern "C" void kernel_launch(void* const* d_in, const int* in_sizes, int n_in,
                              void* d_out, int out_size, void* d_ws, size_t ws_size,
                              hipStream_t stream){
  const float* x          = (const float*)d_in[0];
  const int*   ei         = (const int*)  d_in[1];
  const float* ea         = (const float*)d_in[2];
  const float* preproc_w  = (const float*)d_in[4];
  const float* preproc_b  = (const float*)d_in[5];
  const float* gn_pre_w   = (const float*)d_in[6];
  const float* gn_pre_b   = (const float*)d_in[7];
  const float* gn_pre_ms  = (const float*)d_in[8];
  const float* init_w     = (const float*)d_in[9];
  const float* init_b     = (const float*)d_in[10];
  const float* gn_init_w  = (const float*)d_in[11];
  const float* gn_init_b  = (const float*)d_in[12];
  const float* gn_init_ms = (const float*)d_in[13];
  const float* gate_w1    = (const float*)d_in[14];
  const float* gate_b1    = (const float*)d_in[15];
  const float* gate_w2    = (const float*)d_in[16];
  const float* gate_b2    = (const float*)d_in[17];
  const float* gate_w3    = (const float*)d_in[18];
  const float* gate_b3    = (const float*)d_in[19];
  const float* lin_z_w    = (const float*)d_in[20];
  const float* lin_z_b    = (const float*)d_in[21];
  const float* lin_r_w    = (const float*)d_in[22];
  const float* lin_r_b    = (const float*)d_in[23];
  const float* lin_h_w    = (const float*)d_in[24];
  const float* lin_h_b    = (const float*)d_in[25];
  const float* gn_ggnn_w  = (const float*)d_in[26];
  const float* gn_ggnn_b  = (const float*)d_in[27];
  const float* gn_ggnn_ms = (const float*)d_in[28];
  const float* fc1_w      = (const float*)d_in[29];
  const float* fc1_b      = (const float*)d_in[30];
  const float* gn_fc1_w   = (const float*)d_in[31];
  const float* gn_fc1_b   = (const float*)d_in[32];
  const float* gn_fc1_ms  = (const float*)d_in[33];
  const float* fc2_w      = (const float*)d_in[34];
  const float* fc2_b      = (const float*)d_in[35];

  const int N = in_sizes[3];      // batch has N entries
  const int E = in_sizes[1] / 2;  // edge_index is (2,E)
  const int EN = E + N;

  // ---- workspace layout (5 x 64N-float regions + dis + stats; CSR packed in Qreg) ----
  float* base = (float*)d_ws;
  const size_t R = (size_t)64*N;
  float* h    = base;
  float* h0   = h    + R;
  float* P    = h0   + R;
  float* aggr = P    + R;
  float* Qreg = aggr + R;          // 64N floats repurposed:
  float* dis  = Qreg + R;          // N
  float* stats= dis  + N;          // 128
  size_t need = (5*R + N + 128) * sizeof(float);
  if (ws_size < need) return;

  _Float16* Qh  = (_Float16*)Qreg;                       // 64N halfs = 32N floats
  int*      src = (int*)(Qreg + 32*(size_t)N);           // EN ints
  _Float16* ea2 = (_Float16*)(src + EN);                 // EN halfs
  int* cnt    = (int*)(((uintptr_t)(ea2 + EN) + 15) & ~(uintptr_t)15);
  int* rowptr = cnt + N;
  int* fill   = rowptr + (N+1);
  int* loc    = fill + N;
  int* bsum   = loc + N;           // <=256 ints; fits in Qreg (checked: ~12.3MB of 12.8MB)

  const int GB = 1024;   // node matvec blocks
  const int EB = 3072;   // edge kernel blocks
  const int nb = (N + 255) / 256;  // scan blocks (requires nb <= 256)

  // ---- CSR build (once; reused by all 4 tied layers) ----
  cnt_init_kernel<<<(N+255)/256, 256, 0, stream>>>(cnt, N);
  cnt_kernel<<<(E+255)/256, 256, 0, stream>>>(ei, cnt, E);
  dis_from_cnt_kernel<<<(N+255)/256, 256, 0, stream>>>(cnt, dis, N);
  scan1_kernel<<<nb, 256, 0, stream>>>(cnt, loc, bsum, N);
  scan2_kernel<<<1, 256, 0, stream>>>(bsum, nb);
  scan3_kernel<<<nb, 256, 0, stream>>>(loc, bsum, rowptr, N, EN);
  hipMemsetAsync(fill, 0, (size_t)N*sizeof(int), stream);
  scatter_kernel<<<(EN+255)/256, 256, 0, stream>>>(ei, ea, rowptr, fill, src, ea2, E, N);

  // ---- preproc: x[N,16] @ [16,32] -> P(32) ; norm+relu -> aggr(32) ----
  mm1_kernel<16,32><<<GB, 256, 0, stream>>>(x, preproc_w, preproc_b, P, N);
  hipMemsetAsync(stats, 0, 2*64*sizeof(float), stream);
  norm_stats_kernel<32><<<256, 256, 0, stream>>>(P, N, stats);
  norm_apply_kernel<32,1,0><<<2048, 256, 0, stream>>>(P, stats, gn_pre_w, gn_pre_b, gn_pre_ms, aggr, nullptr, N);

  // ---- init: aggr(32) @ [32,64] -> P(64) ; norm+relu -> h0 and h ----
  mm1_kernel<32,64><<<GB, 256, 0, stream>>>(aggr, init_w, init_b, P, N);
  hipMemsetAsync(stats, 0, 2*64*sizeof(float), stream);
  norm_stats_kernel<64><<<256, 256, 0, stream>>>(P, N, stats);
  norm_apply_kernel<64,1,1><<<2048, 256, 0, stream>>>(P, stats, gn_init_w, gn_init_b, gn_init_ms, h0, h, N);

  // ---- 4 tied GGNN layers ----
  for (int layer = 0; layer < 4; ++layer){
    pq_kernel<<<GB, 256, 0, stream>>>(h, gate_w1, gate_b1, P, Qh, N);
    edge_csr_kernel<<<EB, 256, 0, stream>>>(rowptr, src, ea2, P, Qh, h, dis,
                                            gate_w2, gate_b2, gate_w1 + 128*64,
                                            gate_w3, gate_b3, aggr, N);
    mm2_kernel<0><<<GB, 256, 0, stream>>>(h, aggr, dis, lin_z_w, lin_z_b, P, N);        // z -> P
    gru_kernel<<<GB, 256, 0, stream>>>(h, aggr, dis, P, lin_r_w, lin_r_b, lin_h_w, lin_h_b, N); // hnew -> aggr
    hipMemsetAsync(stats, 0, 2*64*sizeof(float), stream);
    norm_stats_kernel<64><<<256, 256, 0, stream>>>(aggr, N, stats);
    norm_apply_kernel<64,0,0><<<2048, 256, 0, stream>>>(aggr, stats, gn_ggnn_w, gn_ggnn_b, gn_ggnn_ms, h, nullptr, N);
  }

  // ---- fc1: [h0,h] @ [128,64] -> P ; norm+relu -> aggr ----
  mm2_kernel<3><<<GB, 256, 0, stream>>>(h0, h, nullptr, fc1_w, fc1_b, P, N);
  hipMemsetAsync(stats, 0, 2*64*sizeof(float), stream);
  norm_stats_kernel<64><<<256, 256, 0, stream>>>(P, N, stats);
  norm_apply_kernel<64,1,0><<<2048, 256, 0, stream>>>(P, stats, gn_fc1_w, gn_fc1_b, gn_fc1_ms, aggr, nullptr, N);

  // ---- fc2 -> out [N,2] ----
  fc2_kernel<<<(N+255)/256, 256, 0, stream>>>(aggr, fc2_w, fc2_b, (float*)d_out, N);
}

// Round 4
// 1196.450 us; speedup vs baseline: 1.2439x; 1.2439x over previous
//
#include <hip/hip_runtime.h>

#define GN_EPS 1e-5f

typedef _Float16 half8 __attribute__((ext_vector_type(8)));
typedef float floatx4 __attribute__((ext_vector_type(4)));

__device__ __forceinline__ float sigmoidf_(float x){ return 1.0f/(1.0f+__expf(-x)); }
__device__ __forceinline__ float bcast_(float v, int k){
  return __int_as_float(__builtin_amdgcn_readlane(__float_as_int(v), k));
}

// ================= CSR build =================
__global__ void cnt_init_kernel(int* cnt, int n){
  int i = blockIdx.x*blockDim.x+threadIdx.x;
  if (i < n) cnt[i] = 1;  // self loop
}
__global__ void cnt_kernel(const int* __restrict__ ei, int* cnt, int E){
  int e = blockIdx.x*blockDim.x+threadIdx.x;
  if (e < E) atomicAdd(&cnt[ei[E+e]], 1);
}
__global__ void dis_from_cnt_kernel(const int* __restrict__ cnt, float* dis, int n){
  int i = blockIdx.x*blockDim.x+threadIdx.x;
  if (i < n) dis[i] = rsqrtf((float)cnt[i]);
}
__global__ __launch_bounds__(256) void scan1_kernel(const int* __restrict__ cnt,
                                                    int* loc, int* bsum, int n){
  __shared__ int s[256];
  int t = threadIdx.x, i = blockIdx.x*256 + t;
  int v = (i < n) ? cnt[i] : 0;
  s[t] = v; __syncthreads();
  #pragma unroll
  for (int d = 1; d < 256; d <<= 1){
    int u = (t >= d) ? s[t-d] : 0; __syncthreads();
    s[t] += u; __syncthreads();
  }
  if (i < n) loc[i] = s[t] - v;
  if (t == 255) bsum[blockIdx.x] = s[255];
}
__global__ __launch_bounds__(256) void scan2_kernel(int* bsum, int nb){
  __shared__ int s[256];
  int t = threadIdx.x;
  int v = (t < nb) ? bsum[t] : 0;
  s[t] = v; __syncthreads();
  #pragma unroll
  for (int d = 1; d < 256; d <<= 1){
    int u = (t >= d) ? s[t-d] : 0; __syncthreads();
    s[t] += u; __syncthreads();
  }
  if (t < nb) bsum[t] = s[t] - v;
}
__global__ void scan3_kernel(const int* __restrict__ loc, const int* __restrict__ bsum,
                             int* rowptr, int n, int total){
  int i = blockIdx.x*blockDim.x+threadIdx.x;
  if (i < n) rowptr[i] = loc[i] + bsum[i >> 8];
  if (i == 0) rowptr[n] = total;
}
__global__ void scatter_kernel(const int* __restrict__ ei, const float* __restrict__ ea,
                               const int* __restrict__ rowptr, int* fill,
                               int* src, _Float16* ea2, int E, int n){
  int idx = blockIdx.x*blockDim.x+threadIdx.x;
  int tot = E + n;
  if (idx >= tot) return;
  int r, c; float v;
  if (idx < E){ r = ei[idx]; c = ei[E+idx]; v = ea[idx]; }
  else        { r = c = idx - E; v = 1.0f; }
  int j = rowptr[c] + atomicAdd(&fill[c], 1);
  src[j] = r; ea2[j] = (_Float16)v;
}

// ================= small node matvec (preproc/init) =================
template<int K_IN, int C_OUT>
__global__ __launch_bounds__(256) void mm1_kernel(
    const float* __restrict__ x, const float* __restrict__ W,
    const float* __restrict__ b, float* __restrict__ y, int n){
  __shared__ float sW[K_IN*C_OUT];
  for (int i = threadIdx.x; i < K_IN*C_OUT; i += 256) sW[i] = W[i];
  __syncthreads();
  const int lane = threadIdx.x & 63;
  const int col  = (lane < C_OUT) ? lane : 0;
  const float bias = b[col];
  int wid = (blockIdx.x*256 + threadIdx.x) >> 6;
  int nw  = (gridDim.x*256) >> 6;
  for (int i = wid; i < n; i += nw){
    float xv = (lane < K_IN) ? x[(size_t)i*K_IN + lane] : 0.0f;
    float a0 = bias, a1 = 0.0f;
    #pragma unroll
    for (int k = 0; k < K_IN; k += 2){
      a0 += bcast_(xv, k  ) * sW[(k  )*C_OUT + col];
      a1 += bcast_(xv, k+1) * sW[(k+1)*C_OUT + col];
    }
    if (lane < C_OUT) y[(size_t)i*C_OUT + lane] = a0 + a1;
  }
}

// dual-input matvec K=128 (fc1 only): out = [in1,in2] @ W + b
__global__ __launch_bounds__(256) void mm2cat_kernel(
    const float* __restrict__ in1, const float* __restrict__ in2,
    const float* __restrict__ W, const float* __restrict__ b,
    float* __restrict__ out, int n){
  __shared__ float sW[128*64];
  for (int i = threadIdx.x; i < 128*64; i += 256) sW[i] = W[i];
  __syncthreads();
  const int lane = threadIdx.x & 63;
  const float bias = b[lane];
  int wid = (blockIdx.x*256 + threadIdx.x) >> 6;
  int nw  = (gridDim.x*256) >> 6;
  for (int i = wid; i < n; i += nw){
    float v1 = in1[(size_t)i*64 + lane];
    float v2 = in2[(size_t)i*64 + lane];
    float a0 = bias, a1 = 0.f;
    #pragma unroll
    for (int k = 0; k < 64; ++k){
      a0 += bcast_(v1, k) * sW[(k   )*64 + lane];
      a1 += bcast_(v2, k) * sW[(64+k)*64 + lane];
    }
    out[(size_t)i*64 + lane] = a0 + a1;
  }
}

// ================= pq via MFMA: Ph=(f16)(h@w1[0:64]+b1), QH.q=(f16)(h@w1[64:128]) =================
// A input read from QH's H-half (f16 of normed h). 16 nodes per wave.
__global__ __launch_bounds__(256) void pq_mfma_kernel(
    const _Float16* __restrict__ QH, const float* __restrict__ w1,
    const float* __restrict__ b1, _Float16* __restrict__ Ph,
    _Float16* __restrict__ QHq, int n)
{
  __shared__ _Float16 sB[8192];  // [t(8)][kh(2)][g(4)][l(16)][j(8)]
  for (int idx = threadIdx.x; idx < 8192; idx += 256){
    int t=idx>>10, kh=(idx>>9)&1, g=(idx>>7)&3, l=(idx>>3)&15, j=idx&7;
    int kg = (t>=4?64:0) + kh*32 + g*8 + j;
    int col = (t&3)*16 + l;
    sB[idx] = (_Float16)w1[kg*64 + col];
  }
  __syncthreads();
  const int lane = threadIdx.x & 63;
  const int g16 = lane>>4, l16 = lane&15;
  float b1f[4];
  #pragma unroll
  for (int t = 0; t < 4; ++t) b1f[t] = b1[t*16 + l16];

  int wid = (blockIdx.x*blockDim.x + threadIdx.x) >> 6;
  int nw  = (gridDim.x*blockDim.x) >> 6;
  int tiles = (n + 15) >> 4;
  for (int tile = wid; tile < tiles; tile += nw){
    int base = tile*16;
    int na = min(base + l16, n-1);
    half8 af0 = *(const half8*)(QH + (size_t)na*128 + 64 + g16*8);
    half8 af1 = *(const half8*)(QH + (size_t)na*128 + 96 + g16*8);
    floatx4 acc[8];
    #pragma unroll
    for (int t = 0; t < 8; ++t){
      float bv = (t < 4) ? b1f[t] : 0.0f;
      acc[t] = (floatx4){bv, bv, bv, bv};
    }
    #pragma unroll
    for (int t = 0; t < 8; ++t){
      half8 bf0 = *(const half8*)&sB[((t*2+0)*4+g16)*128 + l16*8];
      half8 bf1 = *(const half8*)&sB[((t*2+1)*4+g16)*128 + l16*8];
      acc[t] = __builtin_amdgcn_mfma_f32_16x16x32_f16(af0, bf0, acc[t], 0, 0, 0);
      acc[t] = __builtin_amdgcn_mfma_f32_16x16x32_f16(af1, bf1, acc[t], 0, 0, 0);
    }
    #pragma unroll
    for (int t = 0; t < 8; ++t)
      #pragma unroll
      for (int rg = 0; rg < 4; ++rg){
        int nd = base + g16*4 + rg;
        if (nd < n){
          if (t < 4) Ph [(size_t)nd*64  + t*16 + l16]     = (_Float16)acc[t][rg];
          else       QHq[(size_t)nd*128 + (t-4)*16 + l16] = (_Float16)acc[t][rg];
        }
      }
  }
}

// ================= fused GRU via MFMA: z,r,rh,hc,update in one kernel =================
// h updated IN PLACE. A-frags from QH.h (f16) and aggr*dis (f32->f16).
__global__ __launch_bounds__(256) void gru_mfma_kernel(
    float* __restrict__ h, const float* __restrict__ aggr,
    const float* __restrict__ dis, const _Float16* __restrict__ QH,
    const float* __restrict__ zw, const float* __restrict__ zb,
    const float* __restrict__ rw, const float* __restrict__ rb,
    const float* __restrict__ hw, const float* __restrict__ hb, int n)
{
  __shared__ _Float16 sW[3*8192];      // [m][t(4)][kh(4)][g(4)][l(16)][j(8)]
  __shared__ _Float16 sRH[4][16][72];  // per-wave rh transpose bounce (+pad)
  {
    const float* Ws[3] = {zw, rw, hw};
    for (int m = 0; m < 3; ++m)
      for (int idx = threadIdx.x; idx < 8192; idx += 256){
        int t=(idx>>11)&3, kh=(idx>>9)&3, g=(idx>>7)&3, l=(idx>>3)&15, j=idx&7;
        int kg = kh*32 + g*8 + j;
        sW[m*8192 + idx] = (_Float16)Ws[m][kg*64 + t*16 + l];
      }
  }
  __syncthreads();
  const int lane = threadIdx.x & 63;
  const int g16 = lane>>4, l16 = lane&15;
  const int w = threadIdx.x >> 6;
  float zbf[4], rbf[4], hbf[4];
  #pragma unroll
  for (int t = 0; t < 4; ++t){
    zbf[t] = zb[t*16+l16]; rbf[t] = rb[t*16+l16]; hbf[t] = hb[t*16+l16];
  }
#define GW(m,t,kh) (*(const half8*)&sW[(m)*8192 + (((t)*4+(kh))*4+g16)*128 + l16*8])

  int wid = (blockIdx.x*blockDim.x + threadIdx.x) >> 6;
  int nw  = (gridDim.x*blockDim.x) >> 6;
  int tiles = (n + 15) >> 4;
  for (int tile = wid; tile < tiles; tile += nw){
    int base = tile*16;
    int na = min(base + l16, n-1);
    float dv = dis[na];
    half8 af[4];
    af[0] = *(const half8*)(QH + (size_t)na*128 + 64 + g16*8);
    af[1] = *(const half8*)(QH + (size_t)na*128 + 96 + g16*8);
    #pragma unroll
    for (int kh = 0; kh < 2; ++kh){
      const float* ar = aggr + (size_t)na*64 + kh*32 + g16*8;
      float4 a0 = *(const float4*)ar;
      float4 a1 = *(const float4*)(ar+4);
      half8 t8;
      t8[0]=(_Float16)(a0.x*dv); t8[1]=(_Float16)(a0.y*dv);
      t8[2]=(_Float16)(a0.z*dv); t8[3]=(_Float16)(a0.w*dv);
      t8[4]=(_Float16)(a1.x*dv); t8[5]=(_Float16)(a1.y*dv);
      t8[6]=(_Float16)(a1.z*dv); t8[7]=(_Float16)(a1.w*dv);
      af[2+kh] = t8;
    }
    // z and r (16 MFMAs each)
    floatx4 az[4], ar4[4];
    #pragma unroll
    for (int t = 0; t < 4; ++t){
      az[t]  = (floatx4){zbf[t], zbf[t], zbf[t], zbf[t]};
      ar4[t] = (floatx4){rbf[t], rbf[t], rbf[t], rbf[t]};
      #pragma unroll
      for (int kh = 0; kh < 4; ++kh){
        az[t]  = __builtin_amdgcn_mfma_f32_16x16x32_f16(af[kh], GW(0,t,kh), az[t],  0, 0, 0);
        ar4[t] = __builtin_amdgcn_mfma_f32_16x16x32_f16(af[kh], GW(1,t,kh), ar4[t], 0, 0, 0);
      }
    }
    // z, r epilogue: rh -> LDS (transpose bounce); keep z, h for blend
    float zr[16], hv[16];
    #pragma unroll
    for (int t = 0; t < 4; ++t)
      #pragma unroll
      for (int rg = 0; rg < 4; ++rg){
        int ndc = min(base + g16*4 + rg, n-1);
        float hval = h[(size_t)ndc*64 + t*16 + l16];
        float zv = sigmoidf_(az[t][rg]);
        float rv = sigmoidf_(ar4[t][rg]);
        zr[t*4+rg] = zv; hv[t*4+rg] = hval;
        sRH[w][g16*4+rg][t*16+l16] = (_Float16)(rv*hval);
      }
    asm volatile("s_waitcnt lgkmcnt(0)" ::: "memory");
    __builtin_amdgcn_sched_barrier(0);
    half8 af2_0 = *(const half8*)&sRH[w][l16][g16*8];
    half8 af2_1 = *(const half8*)&sRH[w][l16][32 + g16*8];
    // hc (16 MFMAs)
    floatx4 ah[4];
    #pragma unroll
    for (int t = 0; t < 4; ++t){
      ah[t] = (floatx4){hbf[t], hbf[t], hbf[t], hbf[t]};
      ah[t] = __builtin_amdgcn_mfma_f32_16x16x32_f16(af2_0, GW(2,t,0), ah[t], 0, 0, 0);
      ah[t] = __builtin_amdgcn_mfma_f32_16x16x32_f16(af2_1, GW(2,t,1), ah[t], 0, 0, 0);
      ah[t] = __builtin_amdgcn_mfma_f32_16x16x32_f16(af[2],  GW(2,t,2), ah[t], 0, 0, 0);
      ah[t] = __builtin_amdgcn_mfma_f32_16x16x32_f16(af[3],  GW(2,t,3), ah[t], 0, 0, 0);
    }
    #pragma unroll
    for (int t = 0; t < 4; ++t)
      #pragma unroll
      for (int rg = 0; rg < 4; ++rg){
        int nd = base + g16*4 + rg;
        if (nd < n){
          float hc = fmaxf(ah[t][rg], 0.f);
          float zv = zr[t*4+rg];
          h[(size_t)nd*64 + t*16 + l16] = (1.f - zv)*hv[t*4+rg] + zv*hc;
        }
      }
  }
#undef GW
}

// ================= CSR edge kernel: wave per node, f16 packed gathers =================
__global__ __launch_bounds__(256) void edge_csr_kernel(
    const int* __restrict__ rowptr, const int* __restrict__ src,
    const _Float16* __restrict__ ea2,
    const _Float16* __restrict__ Ph, const _Float16* __restrict__ QH,
    const float* __restrict__ dis,
    const float* __restrict__ w2, const float* __restrict__ b2,
    const float* __restrict__ w1e, const float* __restrict__ w3,
    const float* __restrict__ b3,
    float* __restrict__ aggr, int n)
{
  const int lane = threadIdx.x & 63;
  const int g16  = lane >> 4;
  const int l16  = lane & 15;

  half8 bfrag[4][2];
  #pragma unroll
  for (int t = 0; t < 4; ++t)
    #pragma unroll
    for (int kh = 0; kh < 2; ++kh)
      #pragma unroll
      for (int j = 0; j < 8; ++j)
        bfrag[t][kh][j] = (_Float16)w2[(kh*32 + g16*8 + j)*64 + t*16 + l16];

  float w1f[16];
  #pragma unroll
  for (int kh = 0; kh < 2; ++kh)
    #pragma unroll
    for (int j = 0; j < 8; ++j)
      w1f[kh*8+j] = w1e[kh*32 + g16*8 + j];

  float w3f[4], b2f[4];
  #pragma unroll
  for (int t = 0; t < 4; ++t){ w3f[t] = w3[t*16 + l16]; b2f[t] = b2[t*16 + l16]; }
  const float b3v = b3[0];

  int wid = (blockIdx.x*blockDim.x + threadIdx.x) >> 6;
  int nw  = (gridDim.x*blockDim.x) >> 6;

  for (int c = wid; c < n; c += nw){
    const int base = rowptr[c], endp = rowptr[c+1];
    float pcv[16];
    {
      half8 p0 = *(const half8*)(Ph + (size_t)c*64 + g16*8);
      half8 p1 = *(const half8*)(Ph + (size_t)c*64 + 32 + g16*8);
      #pragma unroll
      for (int j = 0; j < 8; ++j){ pcv[j] = (float)p0[j]; pcv[8+j] = (float)p1[j]; }
    }
    float accv = 0.f;

    for (int t = base; t < endp; t += 16){
      int m = endp - t; if (m > 16) m = 16;
      int j  = t + ((l16 < m) ? l16 : (m-1));
      int r  = src[j];
      float eav = (float)ea2[j];
      float dv  = dis[r];

      half8 afrag[2];
      #pragma unroll
      for (int kh = 0; kh < 2; ++kh){
        half8 hq = *(const half8*)(QH + (size_t)r*128 + kh*32 + g16*8);
        #pragma unroll
        for (int j8 = 0; j8 < 8; ++j8){
          float g = pcv[kh*8+j8] + (float)hq[j8] + eav*w1f[kh*8+j8];
          afrag[kh][j8] = (_Float16)fmaxf(g, 0.0f);
        }
      }

      floatx4 acc[4];
      #pragma unroll
      for (int t4 = 0; t4 < 4; ++t4)
        acc[t4] = (floatx4){b2f[t4], b2f[t4], b2f[t4], b2f[t4]};
      #pragma unroll
      for (int t4 = 0; t4 < 4; ++t4){
        acc[t4] = __builtin_amdgcn_mfma_f32_16x16x32_f16(afrag[0], bfrag[t4][0], acc[t4], 0, 0, 0);
        acc[t4] = __builtin_amdgcn_mfma_f32_16x16x32_f16(afrag[1], bfrag[t4][1], acc[t4], 0, 0, 0);
      }

      float s[4] = {0.f,0.f,0.f,0.f};
      #pragma unroll
      for (int t4 = 0; t4 < 4; ++t4)
        #pragma unroll
        for (int rg = 0; rg < 4; ++rg)
          s[rg] += fmaxf(acc[t4][rg], 0.0f) * w3f[t4];
      #pragma unroll
      for (int rg = 0; rg < 4; ++rg){
        #pragma unroll
        for (int off = 1; off < 16; off <<= 1)
          s[rg] += __shfl_xor(s[rg], off);
        s[rg] = sigmoidf_(s[rg] + b3v);
      }

      for (int i = 0; i < m; ++i){
        float gi = bcast_(s[i & 3], (i >> 2) * 16);
        float f  = gi * bcast_(dv, i);
        int ri   = __builtin_amdgcn_readlane(r, i);
        accv += f * (float)QH[(size_t)ri*128 + 64 + lane];
      }
    }
    aggr[(size_t)c*64 + lane] = accv;
  }
}

// ================= graph norm =================
template<int C>
__global__ __launch_bounds__(256) void norm_stats_kernel(
    const float* __restrict__ x, int n, float* __restrict__ stats){
  __shared__ float ssum[256], ssq[256];
  const int tid = threadIdx.x;
  const int c = tid % C;
  int row = (blockIdx.x*256 + tid) / C;
  int stride = (gridDim.x*256) / C;
  float s = 0.f, q = 0.f;
  for (int i = row; i < n; i += stride){
    float v = x[(size_t)i*C + c];
    s += v; q += v*v;
  }
  ssum[tid] = s; ssq[tid] = q;
  __syncthreads();
  if (tid < C){
    float S = 0.f, Q2 = 0.f;
    for (int t = tid; t < 256; t += C){ S += ssum[t]; Q2 += ssq[t]; }
    atomicAdd(&stats[tid], S);
    atomicAdd(&stats[C + tid], Q2);
  }
}

// H16: also write (f16)v into QH's H-half (C must be 64)
template<int C, int RELU, int DUAL, int H16>
__global__ __launch_bounds__(256) void norm_apply_kernel(
    const float* __restrict__ x, const float* __restrict__ stats,
    const float* __restrict__ w, const float* __restrict__ b,
    const float* __restrict__ ms, float* __restrict__ y,
    float* __restrict__ y2, _Float16* __restrict__ hh, int n){
  const float invN = 1.0f / (float)n;
  size_t idx = blockIdx.x*256 + threadIdx.x;
  size_t step = (size_t)gridDim.x*256;
  size_t tot = (size_t)n*C;
  for (; idx < tot; idx += step){
    int c = idx % C;
    float mean = stats[c] * invN;
    float mm = mean * ms[c];
    float var = stats[C + c]*invN - mm*(2.0f*mean - mm);
    float inv = rsqrtf(fmaxf(var, 0.0f) + GN_EPS);
    float v = (x[idx] - mm)*inv*w[c] + b[c];
    if (RELU) v = fmaxf(v, 0.0f);
    y[idx] = v;
    if (DUAL) y2[idx] = v;
    if (H16) hh[(idx >> 6)*128 + 64 + (idx & 63)] = (_Float16)v;
  }
}

// ================= fc2 =================
__global__ void fc2_kernel(
    const float* __restrict__ x, const float* __restrict__ w,
    const float* __restrict__ b, float* __restrict__ out, int n){
  int i = blockIdx.x*blockDim.x + threadIdx.x;
  if (i >= n) return;
  float a0 = b[0], a1 = b[1];
  const float4* xr = (const float4*)(x + (size_t)i*64);
  #pragma unroll
  for (int k4 = 0; k4 < 16; ++k4){
    float4 v = xr[k4];
    int k = k4*4;
    a0 += v.x*w[(k+0)*2+0] + v.y*w[(k+1)*2+0] + v.z*w[(k+2)*2+0] + v.w*w[(k+3)*2+0];
    a1 += v.x*w[(k+0)*2+1] + v.y*w[(k+1)*2+1] + v.z*w[(k+2)*2+1] + v.w*w[(k+3)*2+1];
  }
  out[i*2+0] = a0;
  out[i*2+1] = a1;
}

extern "C" void kernel_launch(void* const* d_in, const int* in_sizes, int n_in,
                              void* d_out, int out_size, void* d_ws, size_t ws_size,
                              hipStream_t stream){
  const float* x          = (const float*)d_in[0];
  const int*   ei         = (const int*)  d_in[1];
  const float* ea         = (const float*)d_in[2];
  const float* preproc_w  = (const float*)d_in[4];
  const float* preproc_b  = (const float*)d_in[5];
  const float* gn_pre_w   = (const float*)d_in[6];
  const float* gn_pre_b   = (const float*)d_in[7];
  const float* gn_pre_ms  = (const float*)d_in[8];
  const float* init_w     = (const float*)d_in[9];
  const float* init_b     = (const float*)d_in[10];
  const float* gn_init_w  = (const float*)d_in[11];
  const float* gn_init_b  = (const float*)d_in[12];
  const float* gn_init_ms = (const float*)d_in[13];
  const float* gate_w1    = (const float*)d_in[14];
  const float* gate_b1    = (const float*)d_in[15];
  const float* gate_w2    = (const float*)d_in[16];
  const float* gate_b2    = (const float*)d_in[17];
  const float* gate_w3    = (const float*)d_in[18];
  const float* gate_b3    = (const float*)d_in[19];
  const float* lin_z_w    = (const float*)d_in[20];
  const float* lin_z_b    = (const float*)d_in[21];
  const float* lin_r_w    = (const float*)d_in[22];
  const float* lin_r_b    = (const float*)d_in[23];
  const float* lin_h_w    = (const float*)d_in[24];
  const float* lin_h_b    = (const float*)d_in[25];
  const float* gn_ggnn_w  = (const float*)d_in[26];
  const float* gn_ggnn_b  = (const float*)d_in[27];
  const float* gn_ggnn_ms = (const float*)d_in[28];
  const float* fc1_w      = (const float*)d_in[29];
  const float* fc1_b      = (const float*)d_in[30];
  const float* gn_fc1_w   = (const float*)d_in[31];
  const float* gn_fc1_b   = (const float*)d_in[32];
  const float* gn_fc1_ms  = (const float*)d_in[33];
  const float* fc2_w      = (const float*)d_in[34];
  const float* fc2_b      = (const float*)d_in[35];

  const int N = in_sizes[3];
  const int E = in_sizes[1] / 2;
  const int EN = E + N;

  // ---- workspace: 5 R-regions (R = 64N floats), same footprint as round 2/3 ----
  float* base = (float*)d_ws;
  const size_t R = (size_t)64*N;
  float* h     = base;            // f32 [N,64] (also holds [N,32] temp in preproc)
  float* h0    = h    + R;
  float* Preg  = h0   + R;        // Ph f16 [N,64] (32N floats) + CSR arrays (32N floats)
  float* aggr  = Preg + R;
  float* QHreg = aggr + R;        // f16 [N,128]: Q half (0..63) + H half (64..127)
  float* dis   = QHreg + R;
  float* stats = dis + N;
  size_t need = (5*R + N + 128) * sizeof(float);
  if (ws_size < need) return;

  _Float16* Ph = (_Float16*)Preg;
  _Float16* QH = (_Float16*)QHreg;
  int*      src = (int*)(Preg + 32*(size_t)N);
  _Float16* ea2 = (_Float16*)(src + EN);
  int* cnt    = (int*)(((uintptr_t)(ea2 + EN) + 15) & ~(uintptr_t)15);
  int* rowptr = cnt + N;
  int* fill   = rowptr + (N+1);
  int* loc    = fill + N;
  int* bsum   = loc + N;

  const int GB = 1024;   // readlane matvec blocks
  const int RB = 784;    // MFMA node-kernel blocks (3136 waves >= 3125 tiles)
  const int EB = 3072;   // edge kernel blocks
  const int nb = (N + 255) / 256;

  // ---- CSR build (once) ----
  cnt_init_kernel<<<(N+255)/256, 256, 0, stream>>>(cnt, N);
  cnt_kernel<<<(E+255)/256, 256, 0, stream>>>(ei, cnt, E);
  dis_from_cnt_kernel<<<(N+255)/256, 256, 0, stream>>>(cnt, dis, N);
  scan1_kernel<<<nb, 256, 0, stream>>>(cnt, loc, bsum, N);
  scan2_kernel<<<1, 256, 0, stream>>>(bsum, nb);
  scan3_kernel<<<nb, 256, 0, stream>>>(loc, bsum, rowptr, N, EN);
  hipMemsetAsync(fill, 0, (size_t)N*sizeof(int), stream);
  scatter_kernel<<<(EN+255)/256, 256, 0, stream>>>(ei, ea, rowptr, fill, src, ea2, E, N);

  // ---- preproc: x[N,16]@[16,32] -> aggr ; norm+relu -> h (as [N,32]) ----
  mm1_kernel<16,32><<<GB, 256, 0, stream>>>(x, preproc_w, preproc_b, aggr, N);
  hipMemsetAsync(stats, 0, 2*64*sizeof(float), stream);
  norm_stats_kernel<32><<<256, 256, 0, stream>>>(aggr, N, stats);
  norm_apply_kernel<32,1,0,0><<<2048, 256, 0, stream>>>(aggr, stats, gn_pre_w, gn_pre_b, gn_pre_ms, h, nullptr, nullptr, N);

  // ---- init: h[N,32]@[32,64] -> aggr ; norm+relu -> h0, h, QH.h ----
  mm1_kernel<32,64><<<GB, 256, 0, stream>>>(h, init_w, init_b, aggr, N);
  hipMemsetAsync(stats, 0, 2*64*sizeof(float), stream);
  norm_stats_kernel<64><<<256, 256, 0, stream>>>(aggr, N, stats);
  norm_apply_kernel<64,1,1,1><<<2048, 256, 0, stream>>>(aggr, stats, gn_init_w, gn_init_b, gn_init_ms, h0, h, QH, N);

  // ---- 4 tied GGNN layers ----
  for (int layer = 0; layer < 4; ++layer){
    pq_mfma_kernel<<<RB, 256, 0, stream>>>(QH, gate_w1, gate_b1, Ph, QH, N);
    edge_csr_kernel<<<EB, 256, 0, stream>>>(rowptr, src, ea2, Ph, QH, dis,
                                            gate_w2, gate_b2, gate_w1 + 128*64,
                                            gate_w3, gate_b3, aggr, N);
    gru_mfma_kernel<<<RB, 256, 0, stream>>>(h, aggr, dis, QH,
                                            lin_z_w, lin_z_b, lin_r_w, lin_r_b,
                                            lin_h_w, lin_h_b, N);
    hipMemsetAsync(stats, 0, 2*64*sizeof(float), stream);
    norm_stats_kernel<64><<<256, 256, 0, stream>>>(h, N, stats);
    norm_apply_kernel<64,0,0,1><<<2048, 256, 0, stream>>>(h, stats, gn_ggnn_w, gn_ggnn_b, gn_ggnn_ms, h, nullptr, QH, N);
  }

  // ---- fc1: [h0,h]@[128,64] -> aggr ; norm+relu -> h ----
  mm2cat_kernel<<<GB, 256, 0, stream>>>(h0, h, fc1_w, fc1_b, aggr, N);
  hipMemsetAsync(stats, 0, 2*64*sizeof(float), stream);
  norm_stats_kernel<64><<<256, 256, 0, stream>>>(aggr, N, stats);
  norm_apply_kernel<64,1,0,0><<<2048, 256, 0, stream>>>(aggr, stats, gn_fc1_w, gn_fc1_b, gn_fc1_ms, h, nullptr, nullptr, N);

  // ---- fc2 -> out [N,2] ----
  fc2_kernel<<<(N+255)/256, 256, 0, stream>>>(h, fc2_w, fc2_b, (float*)d_out, N);
}

// Round 5
// 871.642 us; speedup vs baseline: 1.7074x; 1.3726x over previous
//
#include <hip/hip_runtime.h>

#define GN_EPS 1e-5f

typedef _Float16 half8 __attribute__((ext_vector_type(8)));
typedef float floatx4 __attribute__((ext_vector_type(4)));

__device__ __forceinline__ float sigmoidf_(float x){ return 1.0f/(1.0f+__expf(-x)); }
__device__ __forceinline__ float bcast_(float v, int k){
  return __int_as_float(__builtin_amdgcn_readlane(__float_as_int(v), k));
}

// ================= CSR build =================
__global__ void cnt_init_kernel(int* cnt, int n){
  int i = blockIdx.x*blockDim.x+threadIdx.x;
  if (i < n) cnt[i] = 1;  // self loop
}
__global__ void cnt_kernel(const int* __restrict__ ei, int* cnt, int E){
  int e = blockIdx.x*blockDim.x+threadIdx.x;
  if (e < E) atomicAdd(&cnt[ei[E+e]], 1);
}
__global__ void dis_from_cnt_kernel(const int* __restrict__ cnt, float* dis, int n){
  int i = blockIdx.x*blockDim.x+threadIdx.x;
  if (i < n) dis[i] = rsqrtf((float)cnt[i]);
}
__global__ __launch_bounds__(256) void scan1_kernel(const int* __restrict__ cnt,
                                                    int* loc, int* bsum, int n){
  __shared__ int s[256];
  int t = threadIdx.x, i = blockIdx.x*256 + t;
  int v = (i < n) ? cnt[i] : 0;
  s[t] = v; __syncthreads();
  #pragma unroll
  for (int d = 1; d < 256; d <<= 1){
    int u = (t >= d) ? s[t-d] : 0; __syncthreads();
    s[t] += u; __syncthreads();
  }
  if (i < n) loc[i] = s[t] - v;
  if (t == 255) bsum[blockIdx.x] = s[255];
}
__global__ __launch_bounds__(256) void scan2_kernel(int* bsum, int nb){
  __shared__ int s[256];
  int t = threadIdx.x;
  int v = (t < nb) ? bsum[t] : 0;
  s[t] = v; __syncthreads();
  #pragma unroll
  for (int d = 1; d < 256; d <<= 1){
    int u = (t >= d) ? s[t-d] : 0; __syncthreads();
    s[t] += u; __syncthreads();
  }
  if (t < nb) bsum[t] = s[t] - v;
}
__global__ void scan3_kernel(const int* __restrict__ loc, const int* __restrict__ bsum,
                             int* rowptr, int n, int total){
  int i = blockIdx.x*blockDim.x+threadIdx.x;
  if (i < n) rowptr[i] = loc[i] + bsum[i >> 8];
  if (i == 0) rowptr[n] = total;
}
__global__ void scatter_kernel(const int* __restrict__ ei, const float* __restrict__ ea,
                               const int* __restrict__ rowptr, int* fill,
                               int* src, _Float16* ea2, int E, int n){
  int idx = blockIdx.x*blockDim.x+threadIdx.x;
  int tot = E + n;
  if (idx >= tot) return;
  int r, c; float v;
  if (idx < E){ r = ei[idx]; c = ei[E+idx]; v = ea[idx]; }
  else        { r = c = idx - E; v = 1.0f; }
  int j = rowptr[c] + atomicAdd(&fill[c], 1);
  src[j] = r; ea2[j] = (_Float16)v;
}

// ================= small node matvec (preproc/init) =================
template<int K_IN, int C_OUT>
__global__ __launch_bounds__(256) void mm1_kernel(
    const float* __restrict__ x, const float* __restrict__ W,
    const float* __restrict__ b, float* __restrict__ y, int n){
  __shared__ float sW[K_IN*C_OUT];
  for (int i = threadIdx.x; i < K_IN*C_OUT; i += 256) sW[i] = W[i];
  __syncthreads();
  const int lane = threadIdx.x & 63;
  const int col  = (lane < C_OUT) ? lane : 0;
  const float bias = b[col];
  int wid = (blockIdx.x*256 + threadIdx.x) >> 6;
  int nw  = (gridDim.x*256) >> 6;
  for (int i = wid; i < n; i += nw){
    float xv = (lane < K_IN) ? x[(size_t)i*K_IN + lane] : 0.0f;
    float a0 = bias, a1 = 0.0f;
    #pragma unroll
    for (int k = 0; k < K_IN; k += 2){
      a0 += bcast_(xv, k  ) * sW[(k  )*C_OUT + col];
      a1 += bcast_(xv, k+1) * sW[(k+1)*C_OUT + col];
    }
    if (lane < C_OUT) y[(size_t)i*C_OUT + lane] = a0 + a1;
  }
}

// dual-input matvec K=128 (fc1 only): out = [in1,in2] @ W + b
__global__ __launch_bounds__(256) void mm2cat_kernel(
    const float* __restrict__ in1, const float* __restrict__ in2,
    const float* __restrict__ W, const float* __restrict__ b,
    float* __restrict__ out, int n){
  __shared__ float sW[128*64];
  for (int i = threadIdx.x; i < 128*64; i += 256) sW[i] = W[i];
  __syncthreads();
  const int lane = threadIdx.x & 63;
  const float bias = b[lane];
  int wid = (blockIdx.x*256 + threadIdx.x) >> 6;
  int nw  = (gridDim.x*256) >> 6;
  for (int i = wid; i < n; i += nw){
    float v1 = in1[(size_t)i*64 + lane];
    float v2 = in2[(size_t)i*64 + lane];
    float a0 = bias, a1 = 0.f;
    #pragma unroll
    for (int k = 0; k < 64; ++k){
      a0 += bcast_(v1, k) * sW[(k   )*64 + lane];
      a1 += bcast_(v2, k) * sW[(64+k)*64 + lane];
    }
    out[(size_t)i*64 + lane] = a0 + a1;
  }
}

// ================= pq via MFMA =================
__global__ __launch_bounds__(256) void pq_mfma_kernel(
    const _Float16* __restrict__ QH, const float* __restrict__ w1,
    const float* __restrict__ b1, _Float16* __restrict__ Ph,
    _Float16* __restrict__ QHq, int n)
{
  __shared__ _Float16 sB[8192];  // [t(8)][kh(2)][g(4)][l(16)][j(8)]
  for (int idx = threadIdx.x; idx < 8192; idx += 256){
    int t=idx>>10, kh=(idx>>9)&1, g=(idx>>7)&3, l=(idx>>3)&15, j=idx&7;
    int kg = (t>=4?64:0) + kh*32 + g*8 + j;
    int col = (t&3)*16 + l;
    sB[idx] = (_Float16)w1[kg*64 + col];
  }
  __syncthreads();
  const int lane = threadIdx.x & 63;
  const int g16 = lane>>4, l16 = lane&15;
  float b1f[4];
  #pragma unroll
  for (int t = 0; t < 4; ++t) b1f[t] = b1[t*16 + l16];

  int wid = (blockIdx.x*blockDim.x + threadIdx.x) >> 6;
  int nw  = (gridDim.x*blockDim.x) >> 6;
  int tiles = (n + 15) >> 4;
  for (int tile = wid; tile < tiles; tile += nw){
    int base = tile*16;
    int na = min(base + l16, n-1);
    half8 af0 = *(const half8*)(QH + (size_t)na*128 + 64 + g16*8);
    half8 af1 = *(const half8*)(QH + (size_t)na*128 + 96 + g16*8);
    floatx4 acc[8];
    #pragma unroll
    for (int t = 0; t < 8; ++t){
      float bv = (t < 4) ? b1f[t] : 0.0f;
      acc[t] = (floatx4){bv, bv, bv, bv};
    }
    #pragma unroll
    for (int t = 0; t < 8; ++t){
      half8 bf0 = *(const half8*)&sB[((t*2+0)*4+g16)*128 + l16*8];
      half8 bf1 = *(const half8*)&sB[((t*2+1)*4+g16)*128 + l16*8];
      acc[t] = __builtin_amdgcn_mfma_f32_16x16x32_f16(af0, bf0, acc[t], 0, 0, 0);
      acc[t] = __builtin_amdgcn_mfma_f32_16x16x32_f16(af1, bf1, acc[t], 0, 0, 0);
    }
    #pragma unroll
    for (int t = 0; t < 8; ++t)
      #pragma unroll
      for (int rg = 0; rg < 4; ++rg){
        int nd = base + g16*4 + rg;
        if (nd < n){
          if (t < 4) Ph [(size_t)nd*64  + t*16 + l16]     = (_Float16)acc[t][rg];
          else       QHq[(size_t)nd*128 + (t-4)*16 + l16] = (_Float16)acc[t][rg];
        }
      }
  }
}

// ================= fused GRU via MFMA + GraphNorm stats =================
__global__ __launch_bounds__(256) void gru_mfma_kernel(
    float* __restrict__ h, const float* __restrict__ aggr,
    const float* __restrict__ dis, const _Float16* __restrict__ QH,
    const float* __restrict__ zw, const float* __restrict__ zb,
    const float* __restrict__ rw, const float* __restrict__ rb,
    const float* __restrict__ hw, const float* __restrict__ hb,
    float* __restrict__ stats, int n)
{
  __shared__ _Float16 sW[3*8192];      // [m][t(4)][kh(4)][g(4)][l(16)][j(8)]
  __shared__ _Float16 sRH[4][16][72];  // per-wave rh transpose bounce (+pad)
  __shared__ float sSt[128];
  if (threadIdx.x < 128) sSt[threadIdx.x] = 0.f;
  {
    const float* Ws[3] = {zw, rw, hw};
    for (int m = 0; m < 3; ++m)
      for (int idx = threadIdx.x; idx < 8192; idx += 256){
        int t=(idx>>11)&3, kh=(idx>>9)&3, g=(idx>>7)&3, l=(idx>>3)&15, j=idx&7;
        int kg = kh*32 + g*8 + j;
        sW[m*8192 + idx] = (_Float16)Ws[m][kg*64 + t*16 + l];
      }
  }
  __syncthreads();
  const int lane = threadIdx.x & 63;
  const int g16 = lane>>4, l16 = lane&15;
  const int w = threadIdx.x >> 6;
  float zbf[4], rbf[4], hbf[4];
  #pragma unroll
  for (int t = 0; t < 4; ++t){
    zbf[t] = zb[t*16+l16]; rbf[t] = rb[t*16+l16]; hbf[t] = hb[t*16+l16];
  }
  float ssum[4] = {0,0,0,0}, ssq[4] = {0,0,0,0};
#define GW(m,t,kh) (*(const half8*)&sW[(m)*8192 + (((t)*4+(kh))*4+g16)*128 + l16*8])

  int wid = (blockIdx.x*blockDim.x + threadIdx.x) >> 6;
  int nw  = (gridDim.x*blockDim.x) >> 6;
  int tiles = (n + 15) >> 4;
  for (int tile = wid; tile < tiles; tile += nw){
    int base = tile*16;
    int na = min(base + l16, n-1);
    float dv = dis[na];
    half8 af[4];
    af[0] = *(const half8*)(QH + (size_t)na*128 + 64 + g16*8);
    af[1] = *(const half8*)(QH + (size_t)na*128 + 96 + g16*8);
    #pragma unroll
    for (int kh = 0; kh < 2; ++kh){
      const float* ar = aggr + (size_t)na*64 + kh*32 + g16*8;
      float4 a0 = *(const float4*)ar;
      float4 a1 = *(const float4*)(ar+4);
      half8 t8;
      t8[0]=(_Float16)(a0.x*dv); t8[1]=(_Float16)(a0.y*dv);
      t8[2]=(_Float16)(a0.z*dv); t8[3]=(_Float16)(a0.w*dv);
      t8[4]=(_Float16)(a1.x*dv); t8[5]=(_Float16)(a1.y*dv);
      t8[6]=(_Float16)(a1.z*dv); t8[7]=(_Float16)(a1.w*dv);
      af[2+kh] = t8;
    }
    // z and r
    floatx4 az[4], ar4[4];
    #pragma unroll
    for (int t = 0; t < 4; ++t){
      az[t]  = (floatx4){zbf[t], zbf[t], zbf[t], zbf[t]};
      ar4[t] = (floatx4){rbf[t], rbf[t], rbf[t], rbf[t]};
      #pragma unroll
      for (int kh = 0; kh < 4; ++kh){
        az[t]  = __builtin_amdgcn_mfma_f32_16x16x32_f16(af[kh], GW(0,t,kh), az[t],  0, 0, 0);
        ar4[t] = __builtin_amdgcn_mfma_f32_16x16x32_f16(af[kh], GW(1,t,kh), ar4[t], 0, 0, 0);
      }
    }
    float zr[16], hv[16];
    #pragma unroll
    for (int t = 0; t < 4; ++t)
      #pragma unroll
      for (int rg = 0; rg < 4; ++rg){
        int ndc = min(base + g16*4 + rg, n-1);
        float hval = h[(size_t)ndc*64 + t*16 + l16];
        float zv = sigmoidf_(az[t][rg]);
        float rv = sigmoidf_(ar4[t][rg]);
        zr[t*4+rg] = zv; hv[t*4+rg] = hval;
        sRH[w][g16*4+rg][t*16+l16] = (_Float16)(rv*hval);
      }
    asm volatile("s_waitcnt lgkmcnt(0)" ::: "memory");
    __builtin_amdgcn_sched_barrier(0);
    half8 af2_0 = *(const half8*)&sRH[w][l16][g16*8];
    half8 af2_1 = *(const half8*)&sRH[w][l16][32 + g16*8];
    // hc
    floatx4 ah[4];
    #pragma unroll
    for (int t = 0; t < 4; ++t){
      ah[t] = (floatx4){hbf[t], hbf[t], hbf[t], hbf[t]};
      ah[t] = __builtin_amdgcn_mfma_f32_16x16x32_f16(af2_0, GW(2,t,0), ah[t], 0, 0, 0);
      ah[t] = __builtin_amdgcn_mfma_f32_16x16x32_f16(af2_1, GW(2,t,1), ah[t], 0, 0, 0);
      ah[t] = __builtin_amdgcn_mfma_f32_16x16x32_f16(af[2],  GW(2,t,2), ah[t], 0, 0, 0);
      ah[t] = __builtin_amdgcn_mfma_f32_16x16x32_f16(af[3],  GW(2,t,3), ah[t], 0, 0, 0);
    }
    #pragma unroll
    for (int t = 0; t < 4; ++t)
      #pragma unroll
      for (int rg = 0; rg < 4; ++rg){
        int nd = base + g16*4 + rg;
        if (nd < n){
          float hc = fmaxf(ah[t][rg], 0.f);
          float zv = zr[t*4+rg];
          float hn = (1.f - zv)*hv[t*4+rg] + zv*hc;
          h[(size_t)nd*64 + t*16 + l16] = hn;
          ssum[t] += hn; ssq[t] += hn*hn;
        }
      }
  }
#undef GW
  #pragma unroll
  for (int t = 0; t < 4; ++t){
    atomicAdd(&sSt[t*16+l16], ssum[t]);
    atomicAdd(&sSt[64+t*16+l16], ssq[t]);
  }
  __syncthreads();
  if (threadIdx.x < 128) atomicAdd(&stats[threadIdx.x], sSt[threadIdx.x]);
}

// ================= CSR edge kernel: batched gathers, prefetched rowptr =================
__global__ __launch_bounds__(256) void edge_csr_kernel(
    const int* __restrict__ rowptr, const int* __restrict__ src,
    const _Float16* __restrict__ ea2,
    const _Float16* __restrict__ Ph, const _Float16* __restrict__ QH,
    const float* __restrict__ dis,
    const float* __restrict__ w2, const float* __restrict__ b2,
    const float* __restrict__ w1e, const float* __restrict__ w3,
    const float* __restrict__ b3,
    float* __restrict__ aggr, int n)
{
  const int lane = threadIdx.x & 63;
  const int g16  = lane >> 6 ? 0 : (lane >> 4);   // lane>>4 (0..3)
  const int l16  = lane & 15;

  half8 bfrag[4][2];
  #pragma unroll
  for (int t = 0; t < 4; ++t)
    #pragma unroll
    for (int kh = 0; kh < 2; ++kh)
      #pragma unroll
      for (int j = 0; j < 8; ++j)
        bfrag[t][kh][j] = (_Float16)w2[(kh*32 + g16*8 + j)*64 + t*16 + l16];

  float w1f[16];
  #pragma unroll
  for (int kh = 0; kh < 2; ++kh)
    #pragma unroll
    for (int j = 0; j < 8; ++j)
      w1f[kh*8+j] = w1e[kh*32 + g16*8 + j];

  float w3f[4], b2f[4];
  #pragma unroll
  for (int t = 0; t < 4; ++t){ w3f[t] = w3[t*16 + l16]; b2f[t] = b2[t*16 + l16]; }
  const float b3v = b3[0];
  const _Float16* QHh = QH + 64;  // H half

  int wid = (blockIdx.x*blockDim.x + threadIdx.x) >> 6;
  int nw  = (gridDim.x*blockDim.x) >> 6;

  int c = wid;
  if (c >= n) return;
  int base = rowptr[c], endp = rowptr[c+1];
  while (true){
    // prefetch next node's row range
    int cn = c + nw;
    int nb2 = 0, ne2 = 0;
    if (cn < n){ nb2 = rowptr[cn]; ne2 = rowptr[cn+1]; }

    float pcv[16];
    {
      half8 p0 = *(const half8*)(Ph + (size_t)c*64 + g16*8);
      half8 p1 = *(const half8*)(Ph + (size_t)c*64 + 32 + g16*8);
      #pragma unroll
      for (int j = 0; j < 8; ++j){ pcv[j] = (float)p0[j]; pcv[8+j] = (float)p1[j]; }
    }
    float accv = 0.f;

    for (int t = base; t < endp; t += 16){
      int m = endp - t; if (m > 16) m = 16;
      int j  = t + ((l16 < m) ? l16 : (m-1));
      int r  = src[j];
      float eav = (float)ea2[j];
      float dv  = dis[r];

      // issue Q-gather
      half8 hq0 = *(const half8*)(QH + (size_t)r*128 + g16*8);
      half8 hq1 = *(const half8*)(QH + (size_t)r*128 + 32 + g16*8);

      // issue ALL 16 h-gathers up-front (batched; clamped rows for i>=m, weight 0)
      _Float16 hv16[16];
      #pragma unroll
      for (int i = 0; i < 16; ++i){
        int ri = __builtin_amdgcn_readlane(r, i);
        hv16[i] = QHh[(size_t)ri*128 + lane];
      }

      // A-frag build (consumes Q-gather)
      half8 afrag[2];
      #pragma unroll
      for (int j8 = 0; j8 < 8; ++j8){
        afrag[0][j8] = (_Float16)fmaxf(pcv[j8]   + (float)hq0[j8] + eav*w1f[j8],   0.0f);
        afrag[1][j8] = (_Float16)fmaxf(pcv[8+j8] + (float)hq1[j8] + eav*w1f[8+j8], 0.0f);
      }

      floatx4 acc[4];
      #pragma unroll
      for (int t4 = 0; t4 < 4; ++t4)
        acc[t4] = (floatx4){b2f[t4], b2f[t4], b2f[t4], b2f[t4]};
      #pragma unroll
      for (int t4 = 0; t4 < 4; ++t4){
        acc[t4] = __builtin_amdgcn_mfma_f32_16x16x32_f16(afrag[0], bfrag[t4][0], acc[t4], 0, 0, 0);
        acc[t4] = __builtin_amdgcn_mfma_f32_16x16x32_f16(afrag[1], bfrag[t4][1], acc[t4], 0, 0, 0);
      }

      float s[4] = {0.f,0.f,0.f,0.f};
      #pragma unroll
      for (int t4 = 0; t4 < 4; ++t4)
        #pragma unroll
        for (int rg = 0; rg < 4; ++rg)
          s[rg] += fmaxf(acc[t4][rg], 0.0f) * w3f[t4];
      #pragma unroll
      for (int rg = 0; rg < 4; ++rg){
        #pragma unroll
        for (int off = 1; off < 16; off <<= 1)
          s[rg] += __shfl_xor(s[rg], off);
        s[rg] = sigmoidf_(s[rg] + b3v);
      }

      // combine (h-gathers long since returned)
      #pragma unroll
      for (int i = 0; i < 16; ++i){
        float gi = bcast_(s[i & 3], (i >> 2) * 16);
        float fv = (i < m) ? gi * bcast_(dv, i) : 0.0f;
        accv += fv * (float)hv16[i];
      }
    }
    aggr[(size_t)c*64 + lane] = accv;
    c = cn;
    if (c >= n) break;
    base = nb2; endp = ne2;
  }
}

// ================= graph norm =================
template<int C>
__global__ __launch_bounds__(256) void norm_stats_kernel(
    const float* __restrict__ x, int n, float* __restrict__ stats){
  __shared__ float ssum[256], ssq[256];
  const int tid = threadIdx.x;
  const int c = tid % C;
  int row = (blockIdx.x*256 + tid) / C;
  int stride = (gridDim.x*256) / C;
  float s = 0.f, q = 0.f;
  for (int i = row; i < n; i += stride){
    float v = x[(size_t)i*C + c];
    s += v; q += v*v;
  }
  ssum[tid] = s; ssq[tid] = q;
  __syncthreads();
  if (tid < C){
    float S = 0.f, Q2 = 0.f;
    for (int t = tid; t < 256; t += C){ S += ssum[t]; Q2 += ssq[t]; }
    atomicAdd(&stats[tid], S);
    atomicAdd(&stats[C + tid], Q2);
  }
}

// H16: also write (f16)v into QH's H-half (C must be 64)
template<int C, int RELU, int DUAL, int H16>
__global__ __launch_bounds__(256) void norm_apply_kernel(
    const float* __restrict__ x, const float* __restrict__ stats,
    const float* __restrict__ w, const float* __restrict__ b,
    const float* __restrict__ ms, float* __restrict__ y,
    float* __restrict__ y2, _Float16* __restrict__ hh, int n){
  const float invN = 1.0f / (float)n;
  size_t idx = blockIdx.x*256 + threadIdx.x;
  size_t step = (size_t)gridDim.x*256;
  size_t tot = (size_t)n*C;
  for (; idx < tot; idx += step){
    int c = idx % C;
    float mean = stats[c] * invN;
    float mm = mean * ms[c];
    float var = stats[C + c]*invN - mm*(2.0f*mean - mm);
    float inv = rsqrtf(fmaxf(var, 0.0f) + GN_EPS);
    float v = (x[idx] - mm)*inv*w[c] + b[c];
    if (RELU) v = fmaxf(v, 0.0f);
    y[idx] = v;
    if (DUAL) y2[idx] = v;
    if (H16) hh[(idx >> 6)*128 + 64 + (idx & 63)] = (_Float16)v;
  }
}

// ================= fc2 =================
__global__ void fc2_kernel(
    const float* __restrict__ x, const float* __restrict__ w,
    const float* __restrict__ b, float* __restrict__ out, int n){
  int i = blockIdx.x*blockDim.x + threadIdx.x;
  if (i >= n) return;
  float a0 = b[0], a1 = b[1];
  const float4* xr = (const float4*)(x + (size_t)i*64);
  #pragma unroll
  for (int k4 = 0; k4 < 16; ++k4){
    float4 v = xr[k4];
    int k = k4*4;
    a0 += v.x*w[(k+0)*2+0] + v.y*w[(k+1)*2+0] + v.z*w[(k+2)*2+0] + v.w*w[(k+3)*2+0];
    a1 += v.x*w[(k+0)*2+1] + v.y*w[(k+1)*2+1] + v.z*w[(k+2)*2+1] + v.w*w[(k+3)*2+1];
  }
  out[i*2+0] = a0;
  out[i*2+1] = a1;
}

extern "C" void kernel_launch(void* const* d_in, const int* in_sizes, int n_in,
                              void* d_out, int out_size, void* d_ws, size_t ws_size,
                              hipStream_t stream){
  const float* x          = (const float*)d_in[0];
  const int*   ei         = (const int*)  d_in[1];
  const float* ea         = (const float*)d_in[2];
  const float* preproc_w  = (const float*)d_in[4];
  const float* preproc_b  = (const float*)d_in[5];
  const float* gn_pre_w   = (const float*)d_in[6];
  const float* gn_pre_b   = (const float*)d_in[7];
  const float* gn_pre_ms  = (const float*)d_in[8];
  const float* init_w     = (const float*)d_in[9];
  const float* init_b     = (const float*)d_in[10];
  const float* gn_init_w  = (const float*)d_in[11];
  const float* gn_init_b  = (const float*)d_in[12];
  const float* gn_init_ms = (const float*)d_in[13];
  const float* gate_w1    = (const float*)d_in[14];
  const float* gate_b1    = (const float*)d_in[15];
  const float* gate_w2    = (const float*)d_in[16];
  const float* gate_b2    = (const float*)d_in[17];
  const float* gate_w3    = (const float*)d_in[18];
  const float* gate_b3    = (const float*)d_in[19];
  const float* lin_z_w    = (const float*)d_in[20];
  const float* lin_z_b    = (const float*)d_in[21];
  const float* lin_r_w    = (const float*)d_in[22];
  const float* lin_r_b    = (const float*)d_in[23];
  const float* lin_h_w    = (const float*)d_in[24];
  const float* lin_h_b    = (const float*)d_in[25];
  const float* gn_ggnn_w  = (const float*)d_in[26];
  const float* gn_ggnn_b  = (const float*)d_in[27];
  const float* gn_ggnn_ms = (const float*)d_in[28];
  const float* fc1_w      = (const float*)d_in[29];
  const float* fc1_b      = (const float*)d_in[30];
  const float* gn_fc1_w   = (const float*)d_in[31];
  const float* gn_fc1_b   = (const float*)d_in[32];
  const float* gn_fc1_ms  = (const float*)d_in[33];
  const float* fc2_w      = (const float*)d_in[34];
  const float* fc2_b      = (const float*)d_in[35];

  const int N = in_sizes[3];
  const int E = in_sizes[1] / 2;
  const int EN = E + N;

  // ---- workspace: 5 R-regions (R = 64N floats), same footprint as rounds 2-4 ----
  float* base = (float*)d_ws;
  const size_t R = (size_t)64*N;
  float* h     = base;
  float* h0    = h    + R;
  float* Preg  = h0   + R;        // Ph f16 [N,64] + CSR arrays
  float* aggr  = Preg + R;
  float* QHreg = aggr + R;        // f16 [N,128]: Q half + H half
  float* dis   = QHreg + R;
  float* stats = dis + N;
  size_t need = (5*R + N + 128) * sizeof(float);
  if (ws_size < need) return;

  _Float16* Ph = (_Float16*)Preg;
  _Float16* QH = (_Float16*)QHreg;
  int*      src = (int*)(Preg + 32*(size_t)N);
  _Float16* ea2 = (_Float16*)(src + EN);
  int* cnt    = (int*)(((uintptr_t)(ea2 + EN) + 15) & ~(uintptr_t)15);
  int* rowptr = cnt + N;
  int* fill   = rowptr + (N+1);
  int* loc    = fill + N;
  int* bsum   = loc + N;

  const int GB = 1024;
  const int RB = 784;    // 3136 waves >= 3125 tiles
  const int EB = 3072;
  const int nb = (N + 255) / 256;

  // ---- CSR build (once) ----
  cnt_init_kernel<<<(N+255)/256, 256, 0, stream>>>(cnt, N);
  cnt_kernel<<<(E+255)/256, 256, 0, stream>>>(ei, cnt, E);
  dis_from_cnt_kernel<<<(N+255)/256, 256, 0, stream>>>(cnt, dis, N);
  scan1_kernel<<<nb, 256, 0, stream>>>(cnt, loc, bsum, N);
  scan2_kernel<<<1, 256, 0, stream>>>(bsum, nb);
  scan3_kernel<<<nb, 256, 0, stream>>>(loc, bsum, rowptr, N, EN);
  hipMemsetAsync(fill, 0, (size_t)N*sizeof(int), stream);
  scatter_kernel<<<(EN+255)/256, 256, 0, stream>>>(ei, ea, rowptr, fill, src, ea2, E, N);

  // ---- preproc ----
  mm1_kernel<16,32><<<GB, 256, 0, stream>>>(x, preproc_w, preproc_b, aggr, N);
  hipMemsetAsync(stats, 0, 2*64*sizeof(float), stream);
  norm_stats_kernel<32><<<256, 256, 0, stream>>>(aggr, N, stats);
  norm_apply_kernel<32,1,0,0><<<2048, 256, 0, stream>>>(aggr, stats, gn_pre_w, gn_pre_b, gn_pre_ms, h, nullptr, nullptr, N);

  // ---- init ----
  mm1_kernel<32,64><<<GB, 256, 0, stream>>>(h, init_w, init_b, aggr, N);
  hipMemsetAsync(stats, 0, 2*64*sizeof(float), stream);
  norm_stats_kernel<64><<<256, 256, 0, stream>>>(aggr, N, stats);
  norm_apply_kernel<64,1,1,1><<<2048, 256, 0, stream>>>(aggr, stats, gn_init_w, gn_init_b, gn_init_ms, h0, h, QH, N);

  // ---- 4 tied GGNN layers ----
  for (int layer = 0; layer < 4; ++layer){
    pq_mfma_kernel<<<RB, 256, 0, stream>>>(QH, gate_w1, gate_b1, Ph, QH, N);
    edge_csr_kernel<<<EB, 256, 0, stream>>>(rowptr, src, ea2, Ph, QH, dis,
                                            gate_w2, gate_b2, gate_w1 + 128*64,
                                            gate_w3, gate_b3, aggr, N);
    hipMemsetAsync(stats, 0, 2*64*sizeof(float), stream);
    gru_mfma_kernel<<<RB, 256, 0, stream>>>(h, aggr, dis, QH,
                                            lin_z_w, lin_z_b, lin_r_w, lin_r_b,
                                            lin_h_w, lin_h_b, stats, N);
    norm_apply_kernel<64,0,0,1><<<2048, 256, 0, stream>>>(h, stats, gn_ggnn_w, gn_ggnn_b, gn_ggnn_ms, h, nullptr, QH, N);
  }

  // ---- fc1 ----
  mm2cat_kernel<<<GB, 256, 0, stream>>>(h0, h, fc1_w, fc1_b, aggr, N);
  hipMemsetAsync(stats, 0, 2*64*sizeof(float), stream);
  norm_stats_kernel<64><<<256, 256, 0, stream>>>(aggr, N, stats);
  norm_apply_kernel<64,1,0,0><<<2048, 256, 0, stream>>>(aggr, stats, gn_fc1_w, gn_fc1_b, gn_fc1_ms, h, nullptr, nullptr, N);

  // ---- fc2 ----
  fc2_kernel<<<(N+255)/256, 256, 0, stream>>>(h, fc2_w, fc2_b, (float*)d_out, N);
}

// Round 6
// 723.833 us; speedup vs baseline: 2.0561x; 1.2042x over previous
//
#include <hip/hip_runtime.h>

#define GN_EPS 1e-5f

typedef _Float16 half8 __attribute__((ext_vector_type(8)));
typedef float floatx4 __attribute__((ext_vector_type(4)));

__device__ __forceinline__ float sigmoidf_(float x){ return 1.0f/(1.0f+__expf(-x)); }
__device__ __forceinline__ float bcast_(float v, int k){
  return __int_as_float(__builtin_amdgcn_readlane(__float_as_int(v), k));
}

// ================= CSR build =================
__global__ void cnt_init_kernel(int* cnt, int n){
  int i = blockIdx.x*blockDim.x+threadIdx.x;
  if (i < n) cnt[i] = 1;  // self loop
}
__global__ void cnt_kernel(const int* __restrict__ ei, int* cnt, int E){
  int e = blockIdx.x*blockDim.x+threadIdx.x;
  if (e < E) atomicAdd(&cnt[ei[E+e]], 1);
}
__global__ void dis_from_cnt_kernel(const int* __restrict__ cnt, float* dis, int n){
  int i = blockIdx.x*blockDim.x+threadIdx.x;
  if (i < n) dis[i] = rsqrtf((float)cnt[i]);
}
__global__ __launch_bounds__(256) void scan1_kernel(const int* __restrict__ cnt,
                                                    int* loc, int* bsum, int n){
  __shared__ int s[256];
  int t = threadIdx.x, i = blockIdx.x*256 + t;
  int v = (i < n) ? cnt[i] : 0;
  s[t] = v; __syncthreads();
  #pragma unroll
  for (int d = 1; d < 256; d <<= 1){
    int u = (t >= d) ? s[t-d] : 0; __syncthreads();
    s[t] += u; __syncthreads();
  }
  if (i < n) loc[i] = s[t] - v;
  if (t == 255) bsum[blockIdx.x] = s[255];
}
__global__ __launch_bounds__(256) void scan2_kernel(int* bsum, int nb){
  __shared__ int s[256];
  int t = threadIdx.x;
  int v = (t < nb) ? bsum[t] : 0;
  s[t] = v; __syncthreads();
  #pragma unroll
  for (int d = 1; d < 256; d <<= 1){
    int u = (t >= d) ? s[t-d] : 0; __syncthreads();
    s[t] += u; __syncthreads();
  }
  if (t < nb) bsum[t] = s[t] - v;
}
__global__ void scan3_kernel(const int* __restrict__ loc, const int* __restrict__ bsum,
                             int* rowptr, int n, int total){
  int i = blockIdx.x*blockDim.x+threadIdx.x;
  if (i < n) rowptr[i] = loc[i] + bsum[i >> 8];
  if (i == 0) rowptr[n] = total;
}
// sd[j] = src | dst<<16 (requires N < 65536)
__global__ void scatter_kernel(const int* __restrict__ ei, const float* __restrict__ ea,
                               const int* __restrict__ rowptr, int* fill,
                               unsigned* sd, _Float16* ea2, int E, int n){
  int idx = blockIdx.x*blockDim.x+threadIdx.x;
  int tot = E + n;
  if (idx >= tot) return;
  int r, c; float v;
  if (idx < E){ r = ei[idx]; c = ei[E+idx]; v = ea[idx]; }
  else        { r = c = idx - E; v = 1.0f; }
  int j = rowptr[c] + atomicAdd(&fill[c], 1);
  sd[j] = (unsigned)r | ((unsigned)c << 16);
  ea2[j] = (_Float16)v;
}

// ================= weight repack (f16, MFMA-fragment order) =================
// wp: [0:8192) w1 (pq layout) | [8192:16384) zw | [16384:24576) rw |
//     [24576:32768) hw | [32768:40960) fc1 | [40960:45056) w2
__global__ __launch_bounds__(256) void wprep_kernel(
    const float* __restrict__ w1, const float* __restrict__ zw,
    const float* __restrict__ rw, const float* __restrict__ hw,
    const float* __restrict__ fw, const float* __restrict__ w2,
    _Float16* __restrict__ wp){
  int idx = blockIdx.x*256 + threadIdx.x;
  if (idx < 8192){
    int t=idx>>10, kh=(idx>>9)&1, g=(idx>>7)&3, l=(idx>>3)&15, j=idx&7;
    int kg=(t>=4?64:0)+kh*32+g*8+j;
    wp[idx] = (_Float16)w1[kg*64 + (t&3)*16 + l];
  } else if (idx < 40960){
    int m=(idx-8192)>>13, k=(idx-8192)&8191;
    int t=(k>>11)&3, kh=(k>>9)&3, g=(k>>7)&3, l=(k>>3)&15, j=k&7;
    const float* W = (m==0)?zw:((m==1)?rw:((m==2)?hw:fw));
    wp[idx] = (_Float16)W[(kh*32+g*8+j)*64 + t*16 + l];
  } else if (idx < 45056){
    int k = idx-40960;
    int t=(k>>10)&3, kh=(k>>9)&1, g=(k>>7)&3, l=(k>>3)&15, j=k&7;
    wp[idx] = (_Float16)w2[(kh*32+g*8+j)*64 + t*16 + l];
  }
}

// ================= small node matvec (preproc/init) =================
template<int K_IN, int C_OUT>
__global__ __launch_bounds__(256) void mm1_kernel(
    const float* __restrict__ x, const float* __restrict__ W,
    const float* __restrict__ b, float* __restrict__ y, int n){
  __shared__ float sW[K_IN*C_OUT];
  for (int i = threadIdx.x; i < K_IN*C_OUT; i += 256) sW[i] = W[i];
  __syncthreads();
  const int lane = threadIdx.x & 63;
  const int col  = (lane < C_OUT) ? lane : 0;
  const float bias = b[col];
  int wid = (blockIdx.x*256 + threadIdx.x) >> 6;
  int nw  = (gridDim.x*256) >> 6;
  for (int i = wid; i < n; i += nw){
    float xv = (lane < K_IN) ? x[(size_t)i*K_IN + lane] : 0.0f;
    float a0 = bias, a1 = 0.0f;
    #pragma unroll
    for (int k = 0; k < K_IN; k += 2){
      a0 += bcast_(xv, k  ) * sW[(k  )*C_OUT + col];
      a1 += bcast_(xv, k+1) * sW[(k+1)*C_OUT + col];
    }
    if (lane < C_OUT) y[(size_t)i*C_OUT + lane] = a0 + a1;
  }
}

// ================= pq via MFMA =================
__global__ __launch_bounds__(256) void pq_mfma_kernel(
    const _Float16* __restrict__ QH, const _Float16* __restrict__ w1p,
    const float* __restrict__ b1, _Float16* __restrict__ Ph,
    _Float16* __restrict__ QHq, int n)
{
  __shared__ _Float16 sB[8192];
  for (int i = threadIdx.x; i < 1024; i += 256)
    ((half8*)sB)[i] = ((const half8*)w1p)[i];
  __syncthreads();
  const int lane = threadIdx.x & 63;
  const int g16 = lane>>4, l16 = lane&15;
  float b1f[4];
  #pragma unroll
  for (int t = 0; t < 4; ++t) b1f[t] = b1[t*16 + l16];

  int wid = (blockIdx.x*blockDim.x + threadIdx.x) >> 6;
  int nw  = (gridDim.x*blockDim.x) >> 6;
  int tiles = (n + 15) >> 4;
  for (int tile = wid; tile < tiles; tile += nw){
    int base = tile*16;
    int na = min(base + l16, n-1);
    half8 af0 = *(const half8*)(QH + (size_t)na*128 + 64 + g16*8);
    half8 af1 = *(const half8*)(QH + (size_t)na*128 + 96 + g16*8);
    floatx4 acc[8];
    #pragma unroll
    for (int t = 0; t < 8; ++t){
      float bv = (t < 4) ? b1f[t] : 0.0f;
      acc[t] = (floatx4){bv, bv, bv, bv};
    }
    #pragma unroll
    for (int t = 0; t < 8; ++t){
      half8 bf0 = *(const half8*)&sB[((t*2+0)*4+g16)*128 + l16*8];
      half8 bf1 = *(const half8*)&sB[((t*2+1)*4+g16)*128 + l16*8];
      acc[t] = __builtin_amdgcn_mfma_f32_16x16x32_f16(af0, bf0, acc[t], 0, 0, 0);
      acc[t] = __builtin_amdgcn_mfma_f32_16x16x32_f16(af1, bf1, acc[t], 0, 0, 0);
    }
    #pragma unroll
    for (int t = 0; t < 8; ++t)
      #pragma unroll
      for (int rg = 0; rg < 4; ++rg){
        int nd = base + g16*4 + rg;
        if (nd < n){
          if (t < 4) Ph [(size_t)nd*64  + t*16 + l16]     = (_Float16)acc[t][rg];
          else       QHq[(size_t)nd*128 + (t-4)*16 + l16] = (_Float16)acc[t][rg];
        }
      }
  }
}

// ================= fused GRU via MFMA + GraphNorm stats =================
__global__ __launch_bounds__(256) void gru_mfma_kernel(
    float* __restrict__ h, const float* __restrict__ aggr,
    const float* __restrict__ dis, const _Float16* __restrict__ QH,
    const _Float16* __restrict__ gwp,
    const float* __restrict__ zb, const float* __restrict__ rb,
    const float* __restrict__ hb,
    float* __restrict__ stats, int n)
{
  __shared__ _Float16 sW[3*8192];
  __shared__ _Float16 sRH[4][16][72];
  __shared__ float sSt[128];
  if (threadIdx.x < 128) sSt[threadIdx.x] = 0.f;
  for (int i = threadIdx.x; i < 3072; i += 256)
    ((half8*)sW)[i] = ((const half8*)gwp)[i];
  __syncthreads();
  const int lane = threadIdx.x & 63;
  const int g16 = lane>>4, l16 = lane&15;
  const int w = threadIdx.x >> 6;
  float zbf[4], rbf[4], hbf[4];
  #pragma unroll
  for (int t = 0; t < 4; ++t){
    zbf[t] = zb[t*16+l16]; rbf[t] = rb[t*16+l16]; hbf[t] = hb[t*16+l16];
  }
  float ssum[4] = {0,0,0,0}, ssq[4] = {0,0,0,0};
#define GW(m,t,kh) (*(const half8*)&sW[(m)*8192 + (((t)*4+(kh))*4+g16)*128 + l16*8])

  int wid = (blockIdx.x*blockDim.x + threadIdx.x) >> 6;
  int nw  = (gridDim.x*blockDim.x) >> 6;
  int tiles = (n + 15) >> 4;
  for (int tile = wid; tile < tiles; tile += nw){
    int base = tile*16;
    int na = min(base + l16, n-1);
    float dv = dis[na];
    half8 af[4];
    af[0] = *(const half8*)(QH + (size_t)na*128 + 64 + g16*8);
    af[1] = *(const half8*)(QH + (size_t)na*128 + 96 + g16*8);
    #pragma unroll
    for (int kh = 0; kh < 2; ++kh){
      const float* ar = aggr + (size_t)na*64 + kh*32 + g16*8;
      float4 a0 = *(const float4*)ar;
      float4 a1 = *(const float4*)(ar+4);
      half8 t8;
      t8[0]=(_Float16)(a0.x*dv); t8[1]=(_Float16)(a0.y*dv);
      t8[2]=(_Float16)(a0.z*dv); t8[3]=(_Float16)(a0.w*dv);
      t8[4]=(_Float16)(a1.x*dv); t8[5]=(_Float16)(a1.y*dv);
      t8[6]=(_Float16)(a1.z*dv); t8[7]=(_Float16)(a1.w*dv);
      af[2+kh] = t8;
    }
    floatx4 az[4], ar4[4];
    #pragma unroll
    for (int t = 0; t < 4; ++t){
      az[t]  = (floatx4){zbf[t], zbf[t], zbf[t], zbf[t]};
      ar4[t] = (floatx4){rbf[t], rbf[t], rbf[t], rbf[t]};
      #pragma unroll
      for (int kh = 0; kh < 4; ++kh){
        az[t]  = __builtin_amdgcn_mfma_f32_16x16x32_f16(af[kh], GW(0,t,kh), az[t],  0, 0, 0);
        ar4[t] = __builtin_amdgcn_mfma_f32_16x16x32_f16(af[kh], GW(1,t,kh), ar4[t], 0, 0, 0);
      }
    }
    float zr[16], hv[16];
    #pragma unroll
    for (int t = 0; t < 4; ++t)
      #pragma unroll
      for (int rg = 0; rg < 4; ++rg){
        int ndc = min(base + g16*4 + rg, n-1);
        float hval = h[(size_t)ndc*64 + t*16 + l16];
        float zv = sigmoidf_(az[t][rg]);
        float rv = sigmoidf_(ar4[t][rg]);
        zr[t*4+rg] = zv; hv[t*4+rg] = hval;
        sRH[w][g16*4+rg][t*16+l16] = (_Float16)(rv*hval);
      }
    asm volatile("s_waitcnt lgkmcnt(0)" ::: "memory");
    __builtin_amdgcn_sched_barrier(0);
    half8 af2_0 = *(const half8*)&sRH[w][l16][g16*8];
    half8 af2_1 = *(const half8*)&sRH[w][l16][32 + g16*8];
    floatx4 ah[4];
    #pragma unroll
    for (int t = 0; t < 4; ++t){
      ah[t] = (floatx4){hbf[t], hbf[t], hbf[t], hbf[t]};
      ah[t] = __builtin_amdgcn_mfma_f32_16x16x32_f16(af2_0, GW(2,t,0), ah[t], 0, 0, 0);
      ah[t] = __builtin_amdgcn_mfma_f32_16x16x32_f16(af2_1, GW(2,t,1), ah[t], 0, 0, 0);
      ah[t] = __builtin_amdgcn_mfma_f32_16x16x32_f16(af[2],  GW(2,t,2), ah[t], 0, 0, 0);
      ah[t] = __builtin_amdgcn_mfma_f32_16x16x32_f16(af[3],  GW(2,t,3), ah[t], 0, 0, 0);
    }
    #pragma unroll
    for (int t = 0; t < 4; ++t)
      #pragma unroll
      for (int rg = 0; rg < 4; ++rg){
        int nd = base + g16*4 + rg;
        if (nd < n){
          float hc = fmaxf(ah[t][rg], 0.f);
          float zv = zr[t*4+rg];
          float hn = (1.f - zv)*hv[t*4+rg] + zv*hc;
          h[(size_t)nd*64 + t*16 + l16] = hn;
          ssum[t] += hn; ssq[t] += hn*hn;
        }
      }
  }
#undef GW
  #pragma unroll
  for (int t = 0; t < 4; ++t){
    atomicAdd(&sSt[t*16+l16], ssum[t]);
    atomicAdd(&sSt[64+t*16+l16], ssq[t]);
  }
  __syncthreads();
  if (threadIdx.x < 128) atomicAdd(&stats[threadIdx.x], sSt[threadIdx.x]);
}

// ================= fc1 via MFMA + fused stats =================
__global__ __launch_bounds__(256) void fc1_mfma_kernel(
    const float* __restrict__ h0, const float* __restrict__ h,
    const _Float16* __restrict__ fp, const float* __restrict__ b,
    float* __restrict__ out, float* __restrict__ stats, int n)
{
  __shared__ _Float16 sB[8192];
  __shared__ float sSt[128];
  if (threadIdx.x < 128) sSt[threadIdx.x] = 0.f;
  for (int i = threadIdx.x; i < 1024; i += 256)
    ((half8*)sB)[i] = ((const half8*)fp)[i];
  __syncthreads();
  const int lane = threadIdx.x & 63;
  const int g16 = lane>>4, l16 = lane&15;
  float bf[4];
  #pragma unroll
  for (int t = 0; t < 4; ++t) bf[t] = b[t*16+l16];
  float ssum[4] = {0,0,0,0}, ssq[4] = {0,0,0,0};

  int wid = (blockIdx.x*blockDim.x + threadIdx.x) >> 6;
  int nw  = (gridDim.x*blockDim.x) >> 6;
  int tiles = (n + 15) >> 4;
  for (int tile = wid; tile < tiles; tile += nw){
    int base = tile*16;
    int na = min(base + l16, n-1);
    half8 af[4];
    #pragma unroll
    for (int kh = 0; kh < 4; ++kh){
      const float* sp = (kh < 2 ? h0 : h) + (size_t)na*64 + (kh&1)*32 + g16*8;
      float4 a0 = *(const float4*)sp;
      float4 a1 = *(const float4*)(sp+4);
      half8 t8;
      t8[0]=(_Float16)a0.x; t8[1]=(_Float16)a0.y; t8[2]=(_Float16)a0.z; t8[3]=(_Float16)a0.w;
      t8[4]=(_Float16)a1.x; t8[5]=(_Float16)a1.y; t8[6]=(_Float16)a1.z; t8[7]=(_Float16)a1.w;
      af[kh] = t8;
    }
    #pragma unroll
    for (int t = 0; t < 4; ++t){
      floatx4 acc = (floatx4){bf[t], bf[t], bf[t], bf[t]};
      #pragma unroll
      for (int kh = 0; kh < 4; ++kh)
        acc = __builtin_amdgcn_mfma_f32_16x16x32_f16(af[kh],
                *(const half8*)&sB[((t*4+kh)*4+g16)*128 + l16*8], acc, 0, 0, 0);
      #pragma unroll
      for (int rg = 0; rg < 4; ++rg){
        int nd = base + g16*4 + rg;
        if (nd < n){
          float v = acc[rg];
          out[(size_t)nd*64 + t*16 + l16] = v;
          ssum[t] += v; ssq[t] += v*v;
        }
      }
    }
  }
  #pragma unroll
  for (int t = 0; t < 4; ++t){
    atomicAdd(&sSt[t*16+l16], ssum[t]);
    atomicAdd(&sSt[64+t*16+l16], ssq[t]);
  }
  __syncthreads();
  if (threadIdx.x < 128) atomicAdd(&stats[threadIdx.x], sSt[threadIdx.x]);
}

// ================= edge kernel: global 16-edge tiles, segmented atomic flush =================
__global__ __launch_bounds__(256) void edge_tile_kernel(
    const unsigned* __restrict__ sd, const _Float16* __restrict__ ea2,
    const _Float16* __restrict__ Ph, const _Float16* __restrict__ QH,
    const float* __restrict__ dis,
    const _Float16* __restrict__ w2p, const float* __restrict__ b2,
    const float* __restrict__ w1e, const float* __restrict__ w3,
    const float* __restrict__ b3,
    float* __restrict__ aggr, int EN)
{
  const int lane = threadIdx.x & 63;
  const int g16  = lane >> 4;
  const int l16  = lane & 15;

  half8 bfrag[4][2];
  #pragma unroll
  for (int t = 0; t < 4; ++t)
    #pragma unroll
    for (int kh = 0; kh < 2; ++kh)
      bfrag[t][kh] = *(const half8*)&w2p[t*1024 + kh*512 + g16*128 + l16*8];

  float w1f[16];
  #pragma unroll
  for (int kh = 0; kh < 2; ++kh)
    #pragma unroll
    for (int j = 0; j < 8; ++j)
      w1f[kh*8+j] = w1e[kh*32 + g16*8 + j];

  float w3f[4], b2f[4];
  #pragma unroll
  for (int t = 0; t < 4; ++t){ w3f[t] = w3[t*16 + l16]; b2f[t] = b2[t*16 + l16]; }
  const float b3v = b3[0];
  const _Float16* QHh = QH + 64;

  int wid = (blockIdx.x*blockDim.x + threadIdx.x) >> 6;
  int nw  = (gridDim.x*blockDim.x) >> 6;
  int tiles = (EN + 15) >> 4;

  for (int tile = wid; tile < tiles; tile += nw){
    int e0 = tile << 4;
    int m = EN - e0; if (m > 16) m = 16;
    int el = e0 + ((l16 < m) ? l16 : (m-1));
    unsigned sdv = sd[el];
    int r = (int)(sdv & 0xffffu);
    int c = (int)(sdv >> 16);
    float eav = (float)ea2[el];
    float dv  = dis[r];

    half8 hq0 = *(const half8*)(QH + (size_t)r*128 + g16*8);
    half8 hq1 = *(const half8*)(QH + (size_t)r*128 + 32 + g16*8);
    half8 p0  = *(const half8*)(Ph + (size_t)c*64 + g16*8);
    half8 p1  = *(const half8*)(Ph + (size_t)c*64 + 32 + g16*8);

    // batched h-gathers (issued before MFMA section consumes anything)
    _Float16 hv16[16];
    #pragma unroll
    for (int i = 0; i < 16; ++i){
      int ri = __builtin_amdgcn_readlane(r, i);
      hv16[i] = QHh[(size_t)ri*128 + lane];
    }

    half8 afrag[2];
    #pragma unroll
    for (int j8 = 0; j8 < 8; ++j8){
      afrag[0][j8] = (_Float16)fmaxf((float)p0[j8] + (float)hq0[j8] + eav*w1f[j8],   0.0f);
      afrag[1][j8] = (_Float16)fmaxf((float)p1[j8] + (float)hq1[j8] + eav*w1f[8+j8], 0.0f);
    }

    floatx4 acc[4];
    #pragma unroll
    for (int t4 = 0; t4 < 4; ++t4)
      acc[t4] = (floatx4){b2f[t4], b2f[t4], b2f[t4], b2f[t4]};
    __builtin_amdgcn_s_setprio(1);
    #pragma unroll
    for (int t4 = 0; t4 < 4; ++t4){
      acc[t4] = __builtin_amdgcn_mfma_f32_16x16x32_f16(afrag[0], bfrag[t4][0], acc[t4], 0, 0, 0);
      acc[t4] = __builtin_amdgcn_mfma_f32_16x16x32_f16(afrag[1], bfrag[t4][1], acc[t4], 0, 0, 0);
    }
    __builtin_amdgcn_s_setprio(0);

    float s[4] = {0.f,0.f,0.f,0.f};
    #pragma unroll
    for (int t4 = 0; t4 < 4; ++t4)
      #pragma unroll
      for (int rg = 0; rg < 4; ++rg)
        s[rg] += fmaxf(acc[t4][rg], 0.0f) * w3f[t4];
    #pragma unroll
    for (int rg = 0; rg < 4; ++rg){
      #pragma unroll
      for (int off = 1; off < 16; off <<= 1)
        s[rg] += __shfl_xor(s[rg], off);
      s[rg] = sigmoidf_(s[rg] + b3v);
    }

    // segmented accumulate + atomic flush (c non-decreasing within tile)
    float accv = 0.f;
    #pragma unroll
    for (int i = 0; i < 16; ++i){
      float gi = bcast_(s[i & 3], (i >> 2) * 16);
      float fv = (i < m) ? gi * bcast_(dv, i) : 0.0f;
      accv += fv * (float)hv16[i];
      int ci = __builtin_amdgcn_readlane(c, i);
      int cn = (i < 15) ? __builtin_amdgcn_readlane(c, i+1) : -1;
      if (cn != ci){
        atomicAdd(&aggr[(size_t)ci*64 + lane], accv);
        accv = 0.f;
      }
    }
  }
}

// ================= graph norm =================
template<int C>
__global__ __launch_bounds__(256) void norm_stats_kernel(
    const float* __restrict__ x, int n, float* __restrict__ stats){
  __shared__ float ssum[256], ssq[256];
  const int tid = threadIdx.x;
  const int c = tid % C;
  int row = (blockIdx.x*256 + tid) / C;
  int stride = (gridDim.x*256) / C;
  float s = 0.f, q = 0.f;
  for (int i = row; i < n; i += stride){
    float v = x[(size_t)i*C + c];
    s += v; q += v*v;
  }
  ssum[tid] = s; ssq[tid] = q;
  __syncthreads();
  if (tid < C){
    float S = 0.f, Q2 = 0.f;
    for (int t = tid; t < 256; t += C){ S += ssum[t]; Q2 += ssq[t]; }
    atomicAdd(&stats[tid], S);
    atomicAdd(&stats[C + tid], Q2);
  }
}

template<int C, int RELU, int DUAL, int H16>
__global__ __launch_bounds__(256) void norm_apply_kernel(
    const float* __restrict__ x, const float* __restrict__ stats,
    const float* __restrict__ w, const float* __restrict__ b,
    const float* __restrict__ ms, float* __restrict__ y,
    float* __restrict__ y2, _Float16* __restrict__ hh, int n){
  const float invN = 1.0f / (float)n;
  size_t idx = blockIdx.x*256 + threadIdx.x;
  size_t step = (size_t)gridDim.x*256;
  size_t tot = (size_t)n*C;
  for (; idx < tot; idx += step){
    int c = idx % C;
    float mean = stats[c] * invN;
    float mm = mean * ms[c];
    float var = stats[C + c]*invN - mm*(2.0f*mean - mm);
    float inv = rsqrtf(fmaxf(var, 0.0f) + GN_EPS);
    float v = (x[idx] - mm)*inv*w[c] + b[c];
    if (RELU) v = fmaxf(v, 0.0f);
    y[idx] = v;
    if (DUAL) y2[idx] = v;
    if (H16) hh[(idx >> 6)*128 + 64 + (idx & 63)] = (_Float16)v;
  }
}

// ================= fc2 =================
__global__ void fc2_kernel(
    const float* __restrict__ x, const float* __restrict__ w,
    const float* __restrict__ b, float* __restrict__ out, int n){
  int i = blockIdx.x*blockDim.x + threadIdx.x;
  if (i >= n) return;
  float a0 = b[0], a1 = b[1];
  const float4* xr = (const float4*)(x + (size_t)i*64);
  #pragma unroll
  for (int k4 = 0; k4 < 16; ++k4){
    float4 v = xr[k4];
    int k = k4*4;
    a0 += v.x*w[(k+0)*2+0] + v.y*w[(k+1)*2+0] + v.z*w[(k+2)*2+0] + v.w*w[(k+3)*2+0];
    a1 += v.x*w[(k+0)*2+1] + v.y*w[(k+1)*2+1] + v.z*w[(k+2)*2+1] + v.w*w[(k+3)*2+1];
  }
  out[i*2+0] = a0;
  out[i*2+1] = a1;
}

extern "C" void kernel_launch(void* const* d_in, const int* in_sizes, int n_in,
                              void* d_out, int out_size, void* d_ws, size_t ws_size,
                              hipStream_t stream){
  const float* x          = (const float*)d_in[0];
  const int*   ei         = (const int*)  d_in[1];
  const float* ea         = (const float*)d_in[2];
  const float* preproc_w  = (const float*)d_in[4];
  const float* preproc_b  = (const float*)d_in[5];
  const float* gn_pre_w   = (const float*)d_in[6];
  const float* gn_pre_b   = (const float*)d_in[7];
  const float* gn_pre_ms  = (const float*)d_in[8];
  const float* init_w     = (const float*)d_in[9];
  const float* init_b     = (const float*)d_in[10];
  const float* gn_init_w  = (const float*)d_in[11];
  const float* gn_init_b  = (const float*)d_in[12];
  const float* gn_init_ms = (const float*)d_in[13];
  const float* gate_w1    = (const float*)d_in[14];
  const float* gate_b1    = (const float*)d_in[15];
  const float* gate_w2    = (const float*)d_in[16];
  const float* gate_b2    = (const float*)d_in[17];
  const float* gate_w3    = (const float*)d_in[18];
  const float* gate_b3    = (const float*)d_in[19];
  const float* lin_z_w    = (const float*)d_in[20];
  const float* lin_z_b    = (const float*)d_in[21];
  const float* lin_r_w    = (const float*)d_in[22];
  const float* lin_r_b    = (const float*)d_in[23];
  const float* lin_h_w    = (const float*)d_in[24];
  const float* lin_h_b    = (const float*)d_in[25];
  const float* gn_ggnn_w  = (const float*)d_in[26];
  const float* gn_ggnn_b  = (const float*)d_in[27];
  const float* gn_ggnn_ms = (const float*)d_in[28];
  const float* fc1_w      = (const float*)d_in[29];
  const float* fc1_b      = (const float*)d_in[30];
  const float* gn_fc1_w   = (const float*)d_in[31];
  const float* gn_fc1_b   = (const float*)d_in[32];
  const float* gn_fc1_ms  = (const float*)d_in[33];
  const float* fc2_w      = (const float*)d_in[34];
  const float* fc2_b      = (const float*)d_in[35];

  const int N = in_sizes[3];
  const int E = in_sizes[1] / 2;
  const int EN = E + N;

  // ---- workspace: 5 R-regions (R = 64N floats) — same footprint as rounds 2-5 ----
  float* base = (float*)d_ws;
  const size_t R = (size_t)64*N;
  float* h     = base;
  float* h0    = h    + R;
  float* Preg  = h0   + R;        // Ph f16 [N,64] | sd | ea2 | wp (f16 weights)
  float* aggr  = Preg + R;        // aggregation target; CSR-build scratch lives here pre-use
  float* QHreg = aggr + R;        // f16 [N,128]: Q half + H half
  float* dis   = QHreg + R;
  float* stats = dis + N;
  size_t need = (5*R + N + 128) * sizeof(float);
  if (ws_size < need || N > 65535) return;

  _Float16* Ph  = (_Float16*)Preg;
  _Float16* QH  = (_Float16*)QHreg;
  unsigned* sd  = (unsigned*)(Preg + 32*(size_t)N);
  _Float16* ea2 = (_Float16*)(sd + EN);
  _Float16* wp  = (_Float16*)(((uintptr_t)(ea2 + EN) + 15) & ~(uintptr_t)15);
  _Float16* w1p = wp;           // 8192
  _Float16* gwp = wp + 8192;    // 3*8192 (z,r,h)
  _Float16* fc1p= wp + 32768;   // 8192
  _Float16* w2p = wp + 40960;   // 4096

  // CSR build scratch (only live before first edge use of aggr)
  int* cnt    = (int*)aggr;
  int* loc    = cnt + N;
  int* fill   = loc + N;
  int* bsum   = fill + N;       // 256
  int* rowptr = bsum + 256;     // N+1

  const int GB = 1024;
  const int RB = 784;    // 3136 waves >= 3125 node tiles
  const int EB = 3072;
  const int nb = (N + 255) / 256;

  // ---- CSR build + weight repack (once) ----
  cnt_init_kernel<<<(N+255)/256, 256, 0, stream>>>(cnt, N);
  cnt_kernel<<<(E+255)/256, 256, 0, stream>>>(ei, cnt, E);
  dis_from_cnt_kernel<<<(N+255)/256, 256, 0, stream>>>(cnt, dis, N);
  scan1_kernel<<<nb, 256, 0, stream>>>(cnt, loc, bsum, N);
  scan2_kernel<<<1, 256, 0, stream>>>(bsum, nb);
  scan3_kernel<<<nb, 256, 0, stream>>>(loc, bsum, rowptr, N, EN);
  hipMemsetAsync(fill, 0, (size_t)N*sizeof(int), stream);
  scatter_kernel<<<(EN+255)/256, 256, 0, stream>>>(ei, ea, rowptr, fill, sd, ea2, E, N);
  wprep_kernel<<<176, 256, 0, stream>>>(gate_w1, lin_z_w, lin_r_w, lin_h_w, fc1_w, gate_w2, wp);

  // ---- preproc ----
  mm1_kernel<16,32><<<GB, 256, 0, stream>>>(x, preproc_w, preproc_b, h0, N);
  hipMemsetAsync(stats, 0, 2*64*sizeof(float), stream);
  norm_stats_kernel<32><<<256, 256, 0, stream>>>(h0, N, stats);
  norm_apply_kernel<32,1,0,0><<<2048, 256, 0, stream>>>(h0, stats, gn_pre_w, gn_pre_b, gn_pre_ms, h, nullptr, nullptr, N);

  // ---- init ----
  mm1_kernel<32,64><<<GB, 256, 0, stream>>>(h, init_w, init_b, h0, N);
  hipMemsetAsync(stats, 0, 2*64*sizeof(float), stream);
  norm_stats_kernel<64><<<256, 256, 0, stream>>>(h0, N, stats);
  norm_apply_kernel<64,1,1,1><<<2048, 256, 0, stream>>>(h0, stats, gn_init_w, gn_init_b, gn_init_ms, h0, h, QH, N);

  // ---- 4 tied GGNN layers ----
  for (int layer = 0; layer < 4; ++layer){
    pq_mfma_kernel<<<RB, 256, 0, stream>>>(QH, w1p, gate_b1, Ph, QH, N);
    hipMemsetAsync(aggr, 0, R*sizeof(float), stream);
    edge_tile_kernel<<<EB, 256, 0, stream>>>(sd, ea2, Ph, QH, dis,
                                             w2p, gate_b2, gate_w1 + 128*64,
                                             gate_w3, gate_b3, aggr, EN);
    hipMemsetAsync(stats, 0, 2*64*sizeof(float), stream);
    gru_mfma_kernel<<<RB, 256, 0, stream>>>(h, aggr, dis, QH, gwp,
                                            lin_z_b, lin_r_b, lin_h_b, stats, N);
    norm_apply_kernel<64,0,0,1><<<2048, 256, 0, stream>>>(h, stats, gn_ggnn_w, gn_ggnn_b, gn_ggnn_ms, h, nullptr, QH, N);
  }

  // ---- fc1 (MFMA + fused stats) ----
  hipMemsetAsync(stats, 0, 2*64*sizeof(float), stream);
  fc1_mfma_kernel<<<RB, 256, 0, stream>>>(h0, h, fc1p, fc1_b, aggr, stats, N);
  norm_apply_kernel<64,1,0,0><<<2048, 256, 0, stream>>>(aggr, stats, gn_fc1_w, gn_fc1_b, gn_fc1_ms, h, nullptr, nullptr, N);

  // ---- fc2 ----
  fc2_kernel<<<(N+255)/256, 256, 0, stream>>>(h, fc2_w, fc2_b, (float*)d_out, N);
}

// Round 7
// 631.478 us; speedup vs baseline: 2.3568x; 1.1463x over previous
//
#include <hip/hip_runtime.h>

#define GN_EPS 1e-5f

typedef _Float16 half8 __attribute__((ext_vector_type(8)));
typedef float floatx4 __attribute__((ext_vector_type(4)));

__device__ __forceinline__ float sigmoidf_(float x){ return 1.0f/(1.0f+__expf(-x)); }
__device__ __forceinline__ float bcast_(float v, int k){
  return __int_as_float(__builtin_amdgcn_readlane(__float_as_int(v), k));
}

// ================= CSR build =================
__global__ void cnt_init_kernel(int* cnt, int n){
  int i = blockIdx.x*blockDim.x+threadIdx.x;
  if (i < n) cnt[i] = 1;  // self loop
}
__global__ void cnt_kernel(const int* __restrict__ ei, int* cnt, int E){
  int e = blockIdx.x*blockDim.x+threadIdx.x;
  if (e < E) atomicAdd(&cnt[ei[E+e]], 1);
}
__global__ void dis_from_cnt_kernel(const int* __restrict__ cnt, float* dis, int n){
  int i = blockIdx.x*blockDim.x+threadIdx.x;
  if (i < n) dis[i] = rsqrtf((float)cnt[i]);
}
__global__ __launch_bounds__(256) void scan1_kernel(const int* __restrict__ cnt,
                                                    int* loc, int* bsum, int n){
  __shared__ int s[256];
  int t = threadIdx.x, i = blockIdx.x*256 + t;
  int v = (i < n) ? cnt[i] : 0;
  s[t] = v; __syncthreads();
  #pragma unroll
  for (int d = 1; d < 256; d <<= 1){
    int u = (t >= d) ? s[t-d] : 0; __syncthreads();
    s[t] += u; __syncthreads();
  }
  if (i < n) loc[i] = s[t] - v;
  if (t == 255) bsum[blockIdx.x] = s[255];
}
__global__ __launch_bounds__(256) void scan2_kernel(int* bsum, int nb){
  __shared__ int s[256];
  int t = threadIdx.x;
  int v = (t < nb) ? bsum[t] : 0;
  s[t] = v; __syncthreads();
  #pragma unroll
  for (int d = 1; d < 256; d <<= 1){
    int u = (t >= d) ? s[t-d] : 0; __syncthreads();
    s[t] += u; __syncthreads();
  }
  if (t < nb) bsum[t] = s[t] - v;
}
__global__ void scan3_kernel(const int* __restrict__ loc, const int* __restrict__ bsum,
                             int* rowptr, int n, int total){
  int i = blockIdx.x*blockDim.x+threadIdx.x;
  if (i < n) rowptr[i] = loc[i] + bsum[i >> 8];
  if (i == 0) rowptr[n] = total;
}
// sd[j] = src | dst<<16 (requires N < 65536)
__global__ void scatter_kernel(const int* __restrict__ ei, const float* __restrict__ ea,
                               const int* __restrict__ rowptr, int* fill,
                               unsigned* sd, _Float16* ea2, int E, int n){
  int idx = blockIdx.x*blockDim.x+threadIdx.x;
  int tot = E + n;
  if (idx >= tot) return;
  int r, c; float v;
  if (idx < E){ r = ei[idx]; c = ei[E+idx]; v = ea[idx]; }
  else        { r = c = idx - E; v = 1.0f; }
  int j = rowptr[c] + atomicAdd(&fill[c], 1);
  sd[j] = (unsigned)r | ((unsigned)c << 16);
  ea2[j] = (_Float16)v;
}

// ================= weight repack (f16, MFMA-fragment order) =================
__global__ __launch_bounds__(256) void wprep_kernel(
    const float* __restrict__ w1, const float* __restrict__ zw,
    const float* __restrict__ rw, const float* __restrict__ hw,
    const float* __restrict__ fw, const float* __restrict__ w2,
    _Float16* __restrict__ wp){
  int idx = blockIdx.x*256 + threadIdx.x;
  if (idx < 8192){
    int t=idx>>10, kh=(idx>>9)&1, g=(idx>>7)&3, l=(idx>>3)&15, j=idx&7;
    int kg=(t>=4?64:0)+kh*32+g*8+j;
    wp[idx] = (_Float16)w1[kg*64 + (t&3)*16 + l];
  } else if (idx < 40960){
    int m=(idx-8192)>>13, k=(idx-8192)&8191;
    int t=(k>>11)&3, kh=(k>>9)&3, g=(k>>7)&3, l=(k>>3)&15, j=k&7;
    const float* W = (m==0)?zw:((m==1)?rw:((m==2)?hw:fw));
    wp[idx] = (_Float16)W[(kh*32+g*8+j)*64 + t*16 + l];
  } else if (idx < 45056){
    int k = idx-40960;
    int t=(k>>10)&3, kh=(k>>9)&1, g=(k>>7)&3, l=(k>>3)&15, j=k&7;
    wp[idx] = (_Float16)w2[(kh*32+g*8+j)*64 + t*16 + l];
  }
}

// ================= small node matvec (preproc/init) =================
template<int K_IN, int C_OUT>
__global__ __launch_bounds__(256) void mm1_kernel(
    const float* __restrict__ x, const float* __restrict__ W,
    const float* __restrict__ b, float* __restrict__ y, int n){
  __shared__ float sW[K_IN*C_OUT];
  for (int i = threadIdx.x; i < K_IN*C_OUT; i += 256) sW[i] = W[i];
  __syncthreads();
  const int lane = threadIdx.x & 63;
  const int col  = (lane < C_OUT) ? lane : 0;
  const float bias = b[col];
  int wid = (blockIdx.x*256 + threadIdx.x) >> 6;
  int nw  = (gridDim.x*256) >> 6;
  for (int i = wid; i < n; i += nw){
    float xv = (lane < K_IN) ? x[(size_t)i*K_IN + lane] : 0.0f;
    float a0 = bias, a1 = 0.0f;
    #pragma unroll
    for (int k = 0; k < K_IN; k += 2){
      a0 += bcast_(xv, k  ) * sW[(k  )*C_OUT + col];
      a1 += bcast_(xv, k+1) * sW[(k+1)*C_OUT + col];
    }
    if (lane < C_OUT) y[(size_t)i*C_OUT + lane] = a0 + a1;
  }
}

// ================= fused GraphNorm-apply + pq via MFMA =================
// hin(raw f32) -> hout(normed f32), optional h0out, QH.h(f16), Ph, QH.q
template<int RELU, int WRITE_H0>
__global__ __launch_bounds__(256) void normpq_kernel(
    const float* __restrict__ hin, float* __restrict__ hout,
    float* __restrict__ h0out,
    const float* __restrict__ stats,
    const float* __restrict__ gw, const float* __restrict__ gb,
    const float* __restrict__ gms,
    const _Float16* __restrict__ w1p, const float* __restrict__ b1,
    _Float16* __restrict__ Ph, _Float16* __restrict__ QH, int n)
{
  __shared__ _Float16 sB[8192];
  __shared__ float sSO[128];
  for (int i = threadIdx.x; i < 1024; i += 256)
    ((half8*)sB)[i] = ((const half8*)w1p)[i];
  if (threadIdx.x < 64){
    int ch = threadIdx.x;
    float invN = 1.0f/(float)n;
    float mean = stats[ch]*invN;
    float mm = mean*gms[ch];
    float var = stats[64+ch]*invN - mm*(2.0f*mean - mm);
    float inv = rsqrtf(fmaxf(var,0.f)+GN_EPS);
    float sc = inv*gw[ch];
    sSO[ch] = sc;
    sSO[64+ch] = gb[ch] - mm*sc;
  }
  __syncthreads();
  const int lane = threadIdx.x & 63;
  const int g16 = lane>>4, l16 = lane&15;
  float scA[8], ofA[8], scB[8], ofB[8];
  #pragma unroll
  for (int j = 0; j < 8; ++j){
    scA[j]=sSO[g16*8+j];    ofA[j]=sSO[64+g16*8+j];
    scB[j]=sSO[32+g16*8+j]; ofB[j]=sSO[96+g16*8+j];
  }
  float b1f[4];
  #pragma unroll
  for (int t = 0; t < 4; ++t) b1f[t] = b1[t*16 + l16];

  int wid = (blockIdx.x*blockDim.x + threadIdx.x) >> 6;
  int nw  = (gridDim.x*blockDim.x) >> 6;
  int tiles = (n + 15) >> 4;
  for (int tile = wid; tile < tiles; tile += nw){
    int base = tile*16;
    int na = min(base + l16, n-1);
    const float* hp = hin + (size_t)na*64;
    float4 a0 = *(const float4*)(hp + g16*8);
    float4 a1 = *(const float4*)(hp + g16*8 + 4);
    float4 c0 = *(const float4*)(hp + 32 + g16*8);
    float4 c1 = *(const float4*)(hp + 32 + g16*8 + 4);
    float va[8] = {a0.x,a0.y,a0.z,a0.w,a1.x,a1.y,a1.z,a1.w};
    float vb[8] = {c0.x,c0.y,c0.z,c0.w,c1.x,c1.y,c1.z,c1.w};
    half8 af0, af1;
    #pragma unroll
    for (int j = 0; j < 8; ++j){
      float v = va[j]*scA[j] + ofA[j];
      if (RELU) v = fmaxf(v, 0.f);
      va[j] = v; af0[j] = (_Float16)v;
      float u = vb[j]*scB[j] + ofB[j];
      if (RELU) u = fmaxf(u, 0.f);
      vb[j] = u; af1[j] = (_Float16)u;
    }
    float* op = hout + (size_t)na*64;
    *(float4*)(op + g16*8)       = (float4){va[0],va[1],va[2],va[3]};
    *(float4*)(op + g16*8 + 4)   = (float4){va[4],va[5],va[6],va[7]};
    *(float4*)(op + 32 + g16*8)  = (float4){vb[0],vb[1],vb[2],vb[3]};
    *(float4*)(op + 32 + g16*8+4)= (float4){vb[4],vb[5],vb[6],vb[7]};
    if (WRITE_H0){
      float* o2 = h0out + (size_t)na*64;
      *(float4*)(o2 + g16*8)       = (float4){va[0],va[1],va[2],va[3]};
      *(float4*)(o2 + g16*8 + 4)   = (float4){va[4],va[5],va[6],va[7]};
      *(float4*)(o2 + 32 + g16*8)  = (float4){vb[0],vb[1],vb[2],vb[3]};
      *(float4*)(o2 + 32 + g16*8+4)= (float4){vb[4],vb[5],vb[6],vb[7]};
    }
    *(half8*)(QH + (size_t)na*128 + 64 + g16*8) = af0;
    *(half8*)(QH + (size_t)na*128 + 96 + g16*8) = af1;

    floatx4 acc[8];
    #pragma unroll
    for (int t = 0; t < 8; ++t){
      float bv = (t < 4) ? b1f[t] : 0.0f;
      acc[t] = (floatx4){bv, bv, bv, bv};
    }
    #pragma unroll
    for (int t = 0; t < 8; ++t){
      half8 bf0 = *(const half8*)&sB[((t*2+0)*4+g16)*128 + l16*8];
      half8 bf1 = *(const half8*)&sB[((t*2+1)*4+g16)*128 + l16*8];
      acc[t] = __builtin_amdgcn_mfma_f32_16x16x32_f16(af0, bf0, acc[t], 0, 0, 0);
      acc[t] = __builtin_amdgcn_mfma_f32_16x16x32_f16(af1, bf1, acc[t], 0, 0, 0);
    }
    #pragma unroll
    for (int t = 0; t < 8; ++t)
      #pragma unroll
      for (int rg = 0; rg < 4; ++rg){
        int nd = base + g16*4 + rg;
        if (nd < n){
          if (t < 4) Ph[(size_t)nd*64  + t*16 + l16]      = (_Float16)acc[t][rg];
          else       QH[(size_t)nd*128 + (t-4)*16 + l16]  = (_Float16)acc[t][rg];
        }
      }
  }
}

// ================= fused GRU via MFMA + GraphNorm stats (+aggr zeroing) =================
__global__ __launch_bounds__(256) void gru_mfma_kernel(
    float* __restrict__ h, float* __restrict__ aggr,
    const float* __restrict__ dis, const _Float16* __restrict__ QH,
    const _Float16* __restrict__ gwp,
    const float* __restrict__ zb, const float* __restrict__ rb,
    const float* __restrict__ hb,
    float* __restrict__ stats, int n)
{
  __shared__ _Float16 sW[3*8192];
  __shared__ _Float16 sRH[4][16][72];
  __shared__ float sSt[128];
  if (threadIdx.x < 128) sSt[threadIdx.x] = 0.f;
  for (int i = threadIdx.x; i < 3072; i += 256)
    ((half8*)sW)[i] = ((const half8*)gwp)[i];
  __syncthreads();
  const int lane = threadIdx.x & 63;
  const int g16 = lane>>4, l16 = lane&15;
  const int w = threadIdx.x >> 6;
  float zbf[4], rbf[4], hbf[4];
  #pragma unroll
  for (int t = 0; t < 4; ++t){
    zbf[t] = zb[t*16+l16]; rbf[t] = rb[t*16+l16]; hbf[t] = hb[t*16+l16];
  }
  float ssum[4] = {0,0,0,0}, ssq[4] = {0,0,0,0};
#define GW(m,t,kh) (*(const half8*)&sW[(m)*8192 + (((t)*4+(kh))*4+g16)*128 + l16*8])

  int wid = (blockIdx.x*blockDim.x + threadIdx.x) >> 6;
  int nw  = (gridDim.x*blockDim.x) >> 6;
  int tiles = (n + 15) >> 4;
  for (int tile = wid; tile < tiles; tile += nw){
    int base = tile*16;
    int na = min(base + l16, n-1);
    float dv = dis[na];
    half8 af[4];
    af[0] = *(const half8*)(QH + (size_t)na*128 + 64 + g16*8);
    af[1] = *(const half8*)(QH + (size_t)na*128 + 96 + g16*8);
    #pragma unroll
    for (int kh = 0; kh < 2; ++kh){
      float* ar = aggr + (size_t)na*64 + kh*32 + g16*8;
      float4 a0 = *(const float4*)ar;
      float4 a1 = *(const float4*)(ar+4);
      // zero for next layer's edge atomics (read-then-clear, same lane)
      *(float4*)(ar)   = (float4){0,0,0,0};
      *(float4*)(ar+4) = (float4){0,0,0,0};
      half8 t8;
      t8[0]=(_Float16)(a0.x*dv); t8[1]=(_Float16)(a0.y*dv);
      t8[2]=(_Float16)(a0.z*dv); t8[3]=(_Float16)(a0.w*dv);
      t8[4]=(_Float16)(a1.x*dv); t8[5]=(_Float16)(a1.y*dv);
      t8[6]=(_Float16)(a1.z*dv); t8[7]=(_Float16)(a1.w*dv);
      af[2+kh] = t8;
    }
    floatx4 az[4], ar4[4];
    #pragma unroll
    for (int t = 0; t < 4; ++t){
      az[t]  = (floatx4){zbf[t], zbf[t], zbf[t], zbf[t]};
      ar4[t] = (floatx4){rbf[t], rbf[t], rbf[t], rbf[t]};
      #pragma unroll
      for (int kh = 0; kh < 4; ++kh){
        az[t]  = __builtin_amdgcn_mfma_f32_16x16x32_f16(af[kh], GW(0,t,kh), az[t],  0, 0, 0);
        ar4[t] = __builtin_amdgcn_mfma_f32_16x16x32_f16(af[kh], GW(1,t,kh), ar4[t], 0, 0, 0);
      }
    }
    float zr[16], hv[16];
    #pragma unroll
    for (int t = 0; t < 4; ++t)
      #pragma unroll
      for (int rg = 0; rg < 4; ++rg){
        int ndc = min(base + g16*4 + rg, n-1);
        float hval = h[(size_t)ndc*64 + t*16 + l16];
        float zv = sigmoidf_(az[t][rg]);
        float rv = sigmoidf_(ar4[t][rg]);
        zr[t*4+rg] = zv; hv[t*4+rg] = hval;
        sRH[w][g16*4+rg][t*16+l16] = (_Float16)(rv*hval);
      }
    asm volatile("s_waitcnt lgkmcnt(0)" ::: "memory");
    __builtin_amdgcn_sched_barrier(0);
    half8 af2_0 = *(const half8*)&sRH[w][l16][g16*8];
    half8 af2_1 = *(const half8*)&sRH[w][l16][32 + g16*8];
    floatx4 ah[4];
    #pragma unroll
    for (int t = 0; t < 4; ++t){
      ah[t] = (floatx4){hbf[t], hbf[t], hbf[t], hbf[t]};
      ah[t] = __builtin_amdgcn_mfma_f32_16x16x32_f16(af2_0, GW(2,t,0), ah[t], 0, 0, 0);
      ah[t] = __builtin_amdgcn_mfma_f32_16x16x32_f16(af2_1, GW(2,t,1), ah[t], 0, 0, 0);
      ah[t] = __builtin_amdgcn_mfma_f32_16x16x32_f16(af[2],  GW(2,t,2), ah[t], 0, 0, 0);
      ah[t] = __builtin_amdgcn_mfma_f32_16x16x32_f16(af[3],  GW(2,t,3), ah[t], 0, 0, 0);
    }
    #pragma unroll
    for (int t = 0; t < 4; ++t)
      #pragma unroll
      for (int rg = 0; rg < 4; ++rg){
        int nd = base + g16*4 + rg;
        if (nd < n){
          float hc = fmaxf(ah[t][rg], 0.f);
          float zv = zr[t*4+rg];
          float hn = (1.f - zv)*hv[t*4+rg] + zv*hc;
          h[(size_t)nd*64 + t*16 + l16] = hn;
          ssum[t] += hn; ssq[t] += hn*hn;
        }
      }
  }
#undef GW
  #pragma unroll
  for (int t = 0; t < 4; ++t){
    atomicAdd(&sSt[t*16+l16], ssum[t]);
    atomicAdd(&sSt[64+t*16+l16], ssq[t]);
  }
  __syncthreads();
  if (threadIdx.x < 128) atomicAdd(&stats[threadIdx.x], sSt[threadIdx.x]);
}

// ================= fc1 via MFMA + fused stats =================
__global__ __launch_bounds__(256) void fc1_mfma_kernel(
    const float* __restrict__ h0, const float* __restrict__ h,
    const _Float16* __restrict__ fp, const float* __restrict__ b,
    float* __restrict__ out, float* __restrict__ stats, int n)
{
  __shared__ _Float16 sB[8192];
  __shared__ float sSt[128];
  if (threadIdx.x < 128) sSt[threadIdx.x] = 0.f;
  for (int i = threadIdx.x; i < 1024; i += 256)
    ((half8*)sB)[i] = ((const half8*)fp)[i];
  __syncthreads();
  const int lane = threadIdx.x & 63;
  const int g16 = lane>>4, l16 = lane&15;
  float bf[4];
  #pragma unroll
  for (int t = 0; t < 4; ++t) bf[t] = b[t*16+l16];
  float ssum[4] = {0,0,0,0}, ssq[4] = {0,0,0,0};

  int wid = (blockIdx.x*blockDim.x + threadIdx.x) >> 6;
  int nw  = (gridDim.x*blockDim.x) >> 6;
  int tiles = (n + 15) >> 4;
  for (int tile = wid; tile < tiles; tile += nw){
    int base = tile*16;
    int na = min(base + l16, n-1);
    half8 af[4];
    #pragma unroll
    for (int kh = 0; kh < 4; ++kh){
      const float* sp = (kh < 2 ? h0 : h) + (size_t)na*64 + (kh&1)*32 + g16*8;
      float4 a0 = *(const float4*)sp;
      float4 a1 = *(const float4*)(sp+4);
      half8 t8;
      t8[0]=(_Float16)a0.x; t8[1]=(_Float16)a0.y; t8[2]=(_Float16)a0.z; t8[3]=(_Float16)a0.w;
      t8[4]=(_Float16)a1.x; t8[5]=(_Float16)a1.y; t8[6]=(_Float16)a1.z; t8[7]=(_Float16)a1.w;
      af[kh] = t8;
    }
    #pragma unroll
    for (int t = 0; t < 4; ++t){
      floatx4 acc = (floatx4){bf[t], bf[t], bf[t], bf[t]};
      #pragma unroll
      for (int kh = 0; kh < 4; ++kh)
        acc = __builtin_amdgcn_mfma_f32_16x16x32_f16(af[kh],
                *(const half8*)&sB[((t*4+kh)*4+g16)*128 + l16*8], acc, 0, 0, 0);
      #pragma unroll
      for (int rg = 0; rg < 4; ++rg){
        int nd = base + g16*4 + rg;
        if (nd < n){
          float v = acc[rg];
          out[(size_t)nd*64 + t*16 + l16] = v;
          ssum[t] += v; ssq[t] += v*v;
        }
      }
    }
  }
  #pragma unroll
  for (int t = 0; t < 4; ++t){
    atomicAdd(&sSt[t*16+l16], ssum[t]);
    atomicAdd(&sSt[64+t*16+l16], ssq[t]);
  }
  __syncthreads();
  if (threadIdx.x < 128) atomicAdd(&stats[threadIdx.x], sSt[threadIdx.x]);
}

// ================= edge kernel: pk-f16 frags, shfl factors, ballot flush =================
__global__ __launch_bounds__(256) void edge_tile_kernel(
    const unsigned* __restrict__ sd, const _Float16* __restrict__ ea2,
    const _Float16* __restrict__ Ph, const _Float16* __restrict__ QH,
    const float* __restrict__ dis,
    const _Float16* __restrict__ w2p, const float* __restrict__ b2,
    const float* __restrict__ w1e, const float* __restrict__ w3,
    const float* __restrict__ b3,
    float* __restrict__ aggr, float* __restrict__ stats, int EN)
{
  // fold the stats zeroing for the following gru into this dispatch
  if (blockIdx.x == 0 && threadIdx.x < 128) stats[threadIdx.x] = 0.f;

  const int lane = threadIdx.x & 63;
  const int g16  = lane >> 4;
  const int l16  = lane & 15;

  half8 bfrag[4][2];
  #pragma unroll
  for (int t = 0; t < 4; ++t)
    #pragma unroll
    for (int kh = 0; kh < 2; ++kh)
      bfrag[t][kh] = *(const half8*)&w2p[t*1024 + kh*512 + g16*128 + l16*8];

  half8 w1h[2];
  #pragma unroll
  for (int kh = 0; kh < 2; ++kh)
    #pragma unroll
    for (int j = 0; j < 8; ++j)
      w1h[kh][j] = (_Float16)w1e[kh*32 + g16*8 + j];

  float w3f[4], b2f[4];
  #pragma unroll
  for (int t = 0; t < 4; ++t){ w3f[t] = w3[t*16 + l16]; b2f[t] = b2[t*16 + l16]; }
  const float b3v = b3[0];
  const _Float16* QHh = QH + 64;

  int wid = (blockIdx.x*blockDim.x + threadIdx.x) >> 6;
  int nw  = (gridDim.x*blockDim.x) >> 6;
  int tiles = (EN + 15) >> 4;

  for (int tile = wid; tile < tiles; tile += nw){
    int e0 = tile << 4;
    int m = EN - e0; if (m > 16) m = 16;
    int el = e0 + ((l16 < m) ? l16 : (m-1));
    unsigned sdv = sd[el];
    int r = (int)(sdv & 0xffffu);
    int c = (int)(sdv >> 16);
    float dv = (l16 < m) ? dis[r] : 0.0f;   // 0-weight for clamped lanes
    _Float16 eavh = ea2[el];

    half8 hq0 = *(const half8*)(QH + (size_t)r*128 + g16*8);
    half8 hq1 = *(const half8*)(QH + (size_t)r*128 + 32 + g16*8);
    half8 p0  = *(const half8*)(Ph + (size_t)c*64 + g16*8);
    half8 p1  = *(const half8*)(Ph + (size_t)c*64 + 32 + g16*8);

    // batched h-gathers, issued before compute consumes anything
    _Float16 hv16[16];
    #pragma unroll
    for (int i = 0; i < 16; ++i){
      int ri = __builtin_amdgcn_readlane(r, i);
      hv16[i] = QHh[(size_t)ri*128 + lane];
    }

    // packed-f16 A-frag build
    half8 e8;
    #pragma unroll
    for (int j = 0; j < 8; ++j) e8[j] = eavh;
    half8 a0h = p0 + hq0 + w1h[0]*e8;
    half8 a1h = p1 + hq1 + w1h[1]*e8;
    #pragma unroll
    for (int j = 0; j < 8; ++j){
      a0h[j] = a0h[j] > (_Float16)0.f ? a0h[j] : (_Float16)0.f;
      a1h[j] = a1h[j] > (_Float16)0.f ? a1h[j] : (_Float16)0.f;
    }

    floatx4 acc[4];
    #pragma unroll
    for (int t4 = 0; t4 < 4; ++t4)
      acc[t4] = (floatx4){b2f[t4], b2f[t4], b2f[t4], b2f[t4]};
    __builtin_amdgcn_s_setprio(1);
    #pragma unroll
    for (int t4 = 0; t4 < 4; ++t4){
      acc[t4] = __builtin_amdgcn_mfma_f32_16x16x32_f16(a0h, bfrag[t4][0], acc[t4], 0, 0, 0);
      acc[t4] = __builtin_amdgcn_mfma_f32_16x16x32_f16(a1h, bfrag[t4][1], acc[t4], 0, 0, 0);
    }
    __builtin_amdgcn_s_setprio(0);

    float s[4] = {0.f,0.f,0.f,0.f};
    #pragma unroll
    for (int t4 = 0; t4 < 4; ++t4)
      #pragma unroll
      for (int rg = 0; rg < 4; ++rg)
        s[rg] += fmaxf(acc[t4][rg], 0.0f) * w3f[t4];
    #pragma unroll
    for (int rg = 0; rg < 4; ++rg){
      #pragma unroll
      for (int off = 1; off < 16; off <<= 1)
        s[rg] += __shfl_xor(s[rg], off);
      s[rg] = sigmoidf_(s[rg] + b3v);
    }

    // per-edge factor f = gate * dis (edge g16*4+rg's dis sits in lane (g16<<4)|(g16*4+rg))
    float fs[4];
    #pragma unroll
    for (int rg = 0; rg < 4; ++rg){
      float dvp = __shfl(dv, (g16 << 4) | (g16*4 + rg));
      fs[rg] = s[rg] * dvp;
    }

    // segment-boundary mask (c non-decreasing; force flush at i=15)
    int cnext = __shfl(c, (lane & 48) | ((l16 + 1) & 15));
    unsigned long long bm = __ballot(c != cnext);
    unsigned bmask = ((unsigned)bm | 0x8000u) & 0xffffu;

    float accv = 0.f;
    #pragma unroll
    for (int i = 0; i < 16; ++i){
      float gi = bcast_(fs[i & 3], (i >> 2) << 4);
      accv = fmaf(gi, (float)hv16[i], accv);
      if ((bmask >> i) & 1){
        int ci = __builtin_amdgcn_readlane(c, i);
        atomicAdd(&aggr[(size_t)ci*64 + lane], accv);
        accv = 0.f;
      }
    }
  }
}

// ================= graph norm (standalone passes) =================
template<int C>
__global__ __launch_bounds__(256) void norm_stats_kernel(
    const float* __restrict__ x, int n, float* __restrict__ stats){
  __shared__ float ssum[256], ssq[256];
  const int tid = threadIdx.x;
  const int c = tid % C;
  int row = (blockIdx.x*256 + tid) / C;
  int stride = (gridDim.x*256) / C;
  float s = 0.f, q = 0.f;
  for (int i = row; i < n; i += stride){
    float v = x[(size_t)i*C + c];
    s += v; q += v*v;
  }
  ssum[tid] = s; ssq[tid] = q;
  __syncthreads();
  if (tid < C){
    float S = 0.f, Q2 = 0.f;
    for (int t = tid; t < 256; t += C){ S += ssum[t]; Q2 += ssq[t]; }
    atomicAdd(&stats[tid], S);
    atomicAdd(&stats[C + tid], Q2);
  }
}

template<int C, int RELU>
__global__ __launch_bounds__(256) void norm_apply_kernel(
    const float* __restrict__ x, const float* __restrict__ stats,
    const float* __restrict__ w, const float* __restrict__ b,
    const float* __restrict__ ms, float* __restrict__ y, int n){
  const float invN = 1.0f / (float)n;
  size_t idx = blockIdx.x*256 + threadIdx.x;
  size_t step = (size_t)gridDim.x*256;
  size_t tot = (size_t)n*C;
  for (; idx < tot; idx += step){
    int c = idx % C;
    float mean = stats[c] * invN;
    float mm = mean * ms[c];
    float var = stats[C + c]*invN - mm*(2.0f*mean - mm);
    float inv = rsqrtf(fmaxf(var, 0.0f) + GN_EPS);
    float v = (x[idx] - mm)*inv*w[c] + b[c];
    if (RELU) v = fmaxf(v, 0.0f);
    y[idx] = v;
  }
}

// ================= fc2 =================
__global__ void fc2_kernel(
    const float* __restrict__ x, const float* __restrict__ w,
    const float* __restrict__ b, float* __restrict__ out, int n){
  int i = blockIdx.x*blockDim.x + threadIdx.x;
  if (i >= n) return;
  float a0 = b[0], a1 = b[1];
  const float4* xr = (const float4*)(x + (size_t)i*64);
  #pragma unroll
  for (int k4 = 0; k4 < 16; ++k4){
    float4 v = xr[k4];
    int k = k4*4;
    a0 += v.x*w[(k+0)*2+0] + v.y*w[(k+1)*2+0] + v.z*w[(k+2)*2+0] + v.w*w[(k+3)*2+0];
    a1 += v.x*w[(k+0)*2+1] + v.y*w[(k+1)*2+1] + v.z*w[(k+2)*2+1] + v.w*w[(k+3)*2+1];
  }
  out[i*2+0] = a0;
  out[i*2+1] = a1;
}

extern "C" void kernel_launch(void* const* d_in, const int* in_sizes, int n_in,
                              void* d_out, int out_size, void* d_ws, size_t ws_size,
                              hipStream_t stream){
  const float* x          = (const float*)d_in[0];
  const int*   ei         = (const int*)  d_in[1];
  const float* ea         = (const float*)d_in[2];
  const float* preproc_w  = (const float*)d_in[4];
  const float* preproc_b  = (const float*)d_in[5];
  const float* gn_pre_w   = (const float*)d_in[6];
  const float* gn_pre_b   = (const float*)d_in[7];
  const float* gn_pre_ms  = (const float*)d_in[8];
  const float* init_w     = (const float*)d_in[9];
  const float* init_b     = (const float*)d_in[10];
  const float* gn_init_w  = (const float*)d_in[11];
  const float* gn_init_b  = (const float*)d_in[12];
  const float* gn_init_ms = (const float*)d_in[13];
  const float* gate_w1    = (const float*)d_in[14];
  const float* gate_b1    = (const float*)d_in[15];
  const float* gate_w2    = (const float*)d_in[16];
  const float* gate_b2    = (const float*)d_in[17];
  const float* gate_w3    = (const float*)d_in[18];
  const float* gate_b3    = (const float*)d_in[19];
  const float* lin_z_w    = (const float*)d_in[20];
  const float* lin_z_b    = (const float*)d_in[21];
  const float* lin_r_w    = (const float*)d_in[22];
  const float* lin_r_b    = (const float*)d_in[23];
  const float* lin_h_w    = (const float*)d_in[24];
  const float* lin_h_b    = (const float*)d_in[25];
  const float* gn_ggnn_w  = (const float*)d_in[26];
  const float* gn_ggnn_b  = (const float*)d_in[27];
  const float* gn_ggnn_ms = (const float*)d_in[28];
  const float* fc1_w      = (const float*)d_in[29];
  const float* fc1_b      = (const float*)d_in[30];
  const float* gn_fc1_w   = (const float*)d_in[31];
  const float* gn_fc1_b   = (const float*)d_in[32];
  const float* gn_fc1_ms  = (const float*)d_in[33];
  const float* fc2_w      = (const float*)d_in[34];
  const float* fc2_b      = (const float*)d_in[35];

  const int N = in_sizes[3];
  const int E = in_sizes[1] / 2;
  const int EN = E + N;

  // ---- workspace: 5 R-regions (R = 64N floats) ----
  float* base = (float*)d_ws;
  const size_t R = (size_t)64*N;
  float* h     = base;
  float* h0    = h    + R;
  float* Preg  = h0   + R;        // Ph f16 [N,64] | sd | ea2 | wp
  float* aggr  = Preg + R;        // aggregation target; CSR scratch pre-use
  float* QHreg = aggr + R;        // f16 [N,128]: Q half + H half
  float* dis   = QHreg + R;
  float* stats = dis + N;
  size_t need = (5*R + N + 128) * sizeof(float);
  if (ws_size < need || N > 65535) return;

  _Float16* Ph  = (_Float16*)Preg;
  _Float16* QH  = (_Float16*)QHreg;
  unsigned* sd  = (unsigned*)(Preg + 32*(size_t)N);
  _Float16* ea2 = (_Float16*)(sd + EN);
  _Float16* wp  = (_Float16*)(((uintptr_t)(ea2 + EN) + 15) & ~(uintptr_t)15);
  _Float16* w1p = wp;           // 8192
  _Float16* gwp = wp + 8192;    // 3*8192
  _Float16* fc1p= wp + 32768;   // 8192
  _Float16* w2p = wp + 40960;   // 4096

  // CSR build scratch (dead after scatter)
  int* cnt    = (int*)aggr;
  int* loc    = cnt + N;
  int* fill   = loc + N;
  int* bsum   = fill + N;
  int* rowptr = bsum + 256;

  const int GB = 1024;
  const int RB = 784;    // 3136 waves >= 3125 node tiles
  const int EB = 3072;
  const int nb = (N + 255) / 256;

  // ---- CSR build + weight repack (once) ----
  cnt_init_kernel<<<(N+255)/256, 256, 0, stream>>>(cnt, N);
  cnt_kernel<<<(E+255)/256, 256, 0, stream>>>(ei, cnt, E);
  dis_from_cnt_kernel<<<(N+255)/256, 256, 0, stream>>>(cnt, dis, N);
  scan1_kernel<<<nb, 256, 0, stream>>>(cnt, loc, bsum, N);
  scan2_kernel<<<1, 256, 0, stream>>>(bsum, nb);
  scan3_kernel<<<nb, 256, 0, stream>>>(loc, bsum, rowptr, N, EN);
  hipMemsetAsync(fill, 0, (size_t)N*sizeof(int), stream);
  scatter_kernel<<<(EN+255)/256, 256, 0, stream>>>(ei, ea, rowptr, fill, sd, ea2, E, N);
  wprep_kernel<<<176, 256, 0, stream>>>(gate_w1, lin_z_w, lin_r_w, lin_h_w, fc1_w, gate_w2, wp);
  hipMemsetAsync(aggr, 0, R*sizeof(float), stream);   // once; gru re-zeroes per layer

  // ---- preproc ----
  mm1_kernel<16,32><<<GB, 256, 0, stream>>>(x, preproc_w, preproc_b, h0, N);
  hipMemsetAsync(stats, 0, 2*64*sizeof(float), stream);
  norm_stats_kernel<32><<<256, 256, 0, stream>>>(h0, N, stats);
  norm_apply_kernel<32,1><<<2048, 256, 0, stream>>>(h0, stats, gn_pre_w, gn_pre_b, gn_pre_ms, h, N);

  // ---- init: h[N,32]@[32,64] -> h0 raw; fused norm+pq -> h0,h,QH,Ph ----
  mm1_kernel<32,64><<<GB, 256, 0, stream>>>(h, init_w, init_b, h0, N);
  hipMemsetAsync(stats, 0, 2*64*sizeof(float), stream);
  norm_stats_kernel<64><<<256, 256, 0, stream>>>(h0, N, stats);
  normpq_kernel<1,1><<<RB, 256, 0, stream>>>(h0, h, h0, stats,
                                             gn_init_w, gn_init_b, gn_init_ms,
                                             w1p, gate_b1, Ph, QH, N);

  // ---- 4 tied GGNN layers (3 dispatches each) ----
  for (int layer = 0; layer < 4; ++layer){
    edge_tile_kernel<<<EB, 256, 0, stream>>>(sd, ea2, Ph, QH, dis,
                                             w2p, gate_b2, gate_w1 + 128*64,
                                             gate_w3, gate_b3, aggr, stats, EN);
    gru_mfma_kernel<<<RB, 256, 0, stream>>>(h, aggr, dis, QH, gwp,
                                            lin_z_b, lin_r_b, lin_h_b, stats, N);
    if (layer < 3)
      normpq_kernel<0,0><<<RB, 256, 0, stream>>>(h, h, nullptr, stats,
                                                 gn_ggnn_w, gn_ggnn_b, gn_ggnn_ms,
                                                 w1p, gate_b1, Ph, QH, N);
    else
      norm_apply_kernel<64,0><<<2048, 256, 0, stream>>>(h, stats, gn_ggnn_w, gn_ggnn_b, gn_ggnn_ms, h, N);
  }

  // ---- fc1 (MFMA + fused stats) ----
  hipMemsetAsync(stats, 0, 2*64*sizeof(float), stream);
  fc1_mfma_kernel<<<RB, 256, 0, stream>>>(h0, h, fc1p, fc1_b, aggr, stats, N);
  norm_apply_kernel<64,1><<<2048, 256, 0, stream>>>(aggr, stats, gn_fc1_w, gn_fc1_b, gn_fc1_ms, h, N);

  // ---- fc2 ----
  fc2_kernel<<<(N+255)/256, 256, 0, stream>>>(h, fc2_w, fc2_b, (float*)d_out, N);
}